// Round 1
// baseline (1765.468 us; speedup 1.0000x reference)
//
#include <hip/hip_runtime.h>
#include <hip/hip_bf16.h>

#define BB 16
#define NN 4096
#define SS 1024
#define KS 32
#define DF 64
#define INC 67
#define C1 64
#define C2 64
#define C3 128
#define ROWS (BB*SS*KS)      /* 524288 */
#define EPSBN 1e-5f
#define F_INF (__builtin_inff())

typedef __bf16 bf16;
typedef __bf16 bfrag __attribute__((ext_vector_type(8)));
typedef float  ffrag __attribute__((ext_vector_type(4)));

// ---- output layout (floats) ----
#define OUT_NXYZ 0
#define OUT_NP   49152
#define OUT_FPS  2146304

// ---- workspace layout (bytes) ----
#define OFF_FPS   0u
#define OFF_NXYZ  65536u
#define OFF_IDX   262144u
#define OFF_STATS 2359296u     /* 3 layers x 64 slots x 256 floats = 196608 B */
#define OFF_ASUM  2555904u     /* 8*16*128 floats = 65536 B */
#define OFF_AMAX  2621440u     /* 65536 B */
#define OFF_BNC   2686976u     /* 3 x 256 floats */
#define OFF_SCALE 2690048u
#define OFF_NP0   2698240u     /* 16384*128 f32 */
#define OFF_YMAX  11086848u    /* 16384*128 f32 */
#define OFF_H1    19475456u    /* 524288*64 bf16 */
#define OFF_H2    86584320u
#define ZERO_BYTES (196608u + 65536u + 65536u)

// ================= FPS (bit-exact vs numpy: no FMA contraction) =================
__global__ __launch_bounds__(256) void fps_kernel(const float* __restrict__ xyz,
                                                  int* __restrict__ fps_i,
                                                  float* __restrict__ nxyz_ws,
                                                  float* __restrict__ out)
{
  __shared__ float lx[NN], ly[NN], lz[NN];
  __shared__ int lfps[SS];
  __shared__ float rv[4]; __shared__ int ri[4];
  __shared__ float cen[4];
  int b = blockIdx.x, t = threadIdx.x;
  const float* xb = xyz + (size_t)b*NN*3;
  for (int p = t; p < NN; p += 256){ lx[p]=xb[p*3]; ly[p]=xb[p*3+1]; lz[p]=xb[p*3+2]; }
  __syncthreads();
  float px[16],py[16],pz[16],pd[16];
  int p0 = t*16;
  #pragma unroll
  for (int j=0;j<16;++j){ px[j]=lx[p0+j]; py[j]=ly[p0+j]; pz[j]=lz[p0+j]; pd[j]=F_INF; }
  if (t==0){ lfps[0]=NN/2; cen[0]=lx[NN/2]; cen[1]=ly[NN/2]; cen[2]=lz[NN/2]; }
  __syncthreads();
  for (int it=1; it<SS; ++it){
    float cx=cen[0], cy=cen[1], cz=cen[2];
    float bv=-1.f; int bi=p0;
    #pragma unroll
    for (int j=0;j<16;++j){
      float dx=px[j]-cx, dy=py[j]-cy, dz=pz[j]-cz;
      float d = __fadd_rn(__fadd_rn(__fmul_rn(dx,dx),__fmul_rn(dy,dy)),__fmul_rn(dz,dz));
      float nd = fminf(pd[j], d);
      pd[j]=nd;
      if (nd > bv){ bv=nd; bi=p0+j; }
    }
    #pragma unroll
    for (int o=32;o;o>>=1){
      float v2=__shfl_down(bv,o); int i2=__shfl_down(bi,o);
      if (v2>bv || (v2==bv && i2<bi)){ bv=v2; bi=i2; }
    }
    if ((t&63)==0){ rv[t>>6]=bv; ri[t>>6]=bi; }
    __syncthreads();
    if (t==0){
      float v=rv[0]; int i=ri[0];
      #pragma unroll
      for (int q=1;q<4;++q){ float v2=rv[q]; int i2=ri[q]; if (v2>v||(v2==v&&i2<i)){v=v2;i=i2;} }
      lfps[it]=i; cen[0]=lx[i]; cen[1]=ly[i]; cen[2]=lz[i];
    }
    __syncthreads();
  }
  for (int s=t; s<SS; s+=256){
    int i = lfps[s];
    fps_i[b*SS+s]=i;
    out[OUT_FPS + b*SS + s] = (float)i;
    float xx=lx[i], yy=ly[i], zz=lz[i];
    int o3 = (b*SS+s)*3;
    out[OUT_NXYZ+o3]=xx; out[OUT_NXYZ+o3+1]=yy; out[OUT_NXYZ+o3+2]=zz;
    nxyz_ws[o3]=xx; nxyz_ws[o3+1]=yy; nxyz_ws[o3+2]=zz;
  }
}

// ================= kNN: 32 smallest dists per (b,s), ties -> lowest index ======
__global__ __launch_bounds__(64) void knn_kernel(const float* __restrict__ xyz,
                                                 const float* __restrict__ nxyz,
                                                 int* __restrict__ knn)
{
  __shared__ float ld[NN];
  int lane = threadIdx.x;
  int bs = blockIdx.x;
  int b = bs >> 10;
  const float* xb = xyz + (size_t)b*NN*3;
  float sx=nxyz[bs*3], sy=nxyz[bs*3+1], sz=nxyz[bs*3+2];
  float gv[8]; int gi[8];
  float lv = F_INF; int li = 0;
  #pragma unroll
  for (int g=0; g<8; ++g){
    float bgv = F_INF; int bgi = 0;
    #pragma unroll
    for (int jj=0; jj<8; ++jj){
      int p = (g*8+jj)*64 + lane;
      float dx=xb[p*3]-sx, dy=xb[p*3+1]-sy, dz=xb[p*3+2]-sz;
      float d = dx*dx+dy*dy+dz*dz;
      ld[p] = d;
      if (d < bgv){ bgv=d; bgi=p; }
    }
    gv[g]=bgv; gi[g]=bgi;
    if (bgv < lv){ lv=bgv; li=bgi; }
  }
  int kept = 0;
  for (int it=0; it<KS; ++it){
    float v=lv; int i=li;
    #pragma unroll
    for (int o=32;o;o>>=1){
      float v2=__shfl_xor(v,o); int i2=__shfl_xor(i,o);
      if (v2<v || (v2==v && i2<i)){ v=v2; i=i2; }
    }
    if (lane==it) kept = i;
    if ((i & 63) == lane){
      int j = i >> 6;
      ld[i] = F_INF;
      int g = j >> 3;
      float bgv=F_INF; int bgi=0;
      for (int jj=0;jj<8;++jj){
        int p = (g*8+jj)*64 + lane;
        float d = ld[p];
        if (d<bgv){bgv=d;bgi=p;}
      }
      #pragma unroll
      for (int q=0;q<8;++q){ if (q==g){ gv[q]=bgv; gi[q]=bgi; } }
      lv=F_INF; li=0;
      #pragma unroll
      for (int q=0;q<8;++q){ if (gv[q]<lv){ lv=gv[q]; li=gi[q]; } }
    }
  }
  if (lane < KS) knn[bs*KS + lane] = kept;
}

// ================= conv1: gather + MFMA (K=67 padded 96) -> h1 + stats =========
__global__ __launch_bounds__(256) void conv1_kernel(const float* __restrict__ xyz,
                                                    const float* __restrict__ points,
                                                    const float* __restrict__ W0,
                                                    const float* __restrict__ b0,
                                                    const float* __restrict__ nxyz,
                                                    const int* __restrict__ knn,
                                                    bf16* __restrict__ h1,
                                                    float* __restrict__ stats)
{
  __shared__ __align__(16) bf16 As[64][104];
  __shared__ __align__(16) bf16 Bs[64][104];
  __shared__ float s1[C1], s2[C1];
  int t = threadIdx.x;
  int Rbase = blockIdx.x * 64;
  if (t < C1){ s1[t]=0.f; s2[t]=0.f; }
  { // stage B (weights, channel-reordered: feat first, rel at 64..66, zeros to 95)
    int o = t >> 2, q = t & 3;
    const float* wr = W0 + o*INC;
    for (int cc = q*24; cc < q*24+24; ++cc){
      float w;
      if (cc < 64) w = wr[3+cc];
      else if (cc < 67) w = wr[cc-64];
      else w = 0.f;
      Bs[o][cc] = (bf16)w;
    }
  }
  { // stage A (gathered activations)
    int r = t >> 2, q = t & 3;
    int R = Rbase + r;
    int bs = R >> 5;
    int bIdx = bs >> 10;
    int nI = knn[R];
    const float* pr = points + ((size_t)(bIdx*NN + nI))*DF + q*16;
    float4 f0 = *(const float4*)(pr);
    float4 f1 = *(const float4*)(pr+4);
    float4 f2 = *(const float4*)(pr+8);
    float4 f3 = *(const float4*)(pr+12);
    bf16* ap = &As[r][q*16];
    ap[0]=(bf16)f0.x; ap[1]=(bf16)f0.y; ap[2]=(bf16)f0.z; ap[3]=(bf16)f0.w;
    ap[4]=(bf16)f1.x; ap[5]=(bf16)f1.y; ap[6]=(bf16)f1.z; ap[7]=(bf16)f1.w;
    ap[8]=(bf16)f2.x; ap[9]=(bf16)f2.y; ap[10]=(bf16)f2.z; ap[11]=(bf16)f2.w;
    ap[12]=(bf16)f3.x; ap[13]=(bf16)f3.y; ap[14]=(bf16)f3.z; ap[15]=(bf16)f3.w;
    if (q==0){
      const float* xr = xyz + ((size_t)(bIdx*NN + nI))*3;
      const float* nr = nxyz + bs*3;
      As[r][64]=(bf16)(xr[0]-nr[0]);
      As[r][65]=(bf16)(xr[1]-nr[1]);
      As[r][66]=(bf16)(xr[2]-nr[2]);
      for (int cc=67; cc<96; ++cc) As[r][cc]=(bf16)0.f;
    }
  }
  __syncthreads();
  int wv = t >> 6, lane = t & 63;
  int row16 = wv * 16;
  int arow = lane & 15, kgrp = lane >> 4;
  ffrag acc[4] = {};
  #pragma unroll
  for (int kc = 0; kc < 3; ++kc){
    bfrag af = *(const bfrag*)&As[row16 + arow][kc*32 + kgrp*8];
    #pragma unroll
    for (int nt = 0; nt < 4; ++nt){
      bfrag bfv = *(const bfrag*)&Bs[nt*16 + arow][kc*32 + kgrp*8];
      acc[nt] = __builtin_amdgcn_mfma_f32_16x16x32_bf16(af, bfv, acc[nt], 0,0,0);
    }
  }
  #pragma unroll
  for (int nt=0; nt<4; ++nt){
    int c = nt*16 + arow;
    float bias = b0[c];
    float ls1=0.f, ls2=0.f;
    #pragma unroll
    for (int r=0;r<4;++r){
      float y = acc[nt][r] + bias;
      int grow = Rbase + row16 + kgrp*4 + r;
      h1[(size_t)grow*C1 + c] = (bf16)y;
      ls1 += y; ls2 += y*y;
    }
    ls1 += __shfl_xor(ls1, 16); ls1 += __shfl_xor(ls1, 32);
    ls2 += __shfl_xor(ls2, 16); ls2 += __shfl_xor(ls2, 32);
    if (kgrp==0){ atomicAdd(&s1[c], ls1); atomicAdd(&s2[c], ls2); }
  }
  __syncthreads();
  if (t < C1){
    float* gp = stats + (blockIdx.x & 63)*256;
    atomicAdd(&gp[t], s1[t]);
    atomicAdd(&gp[128 + t], s2[t]);
  }
}

// ================= BN finalize -> affine coeffs ================================
__global__ void bnfin_kernel(const float* __restrict__ stats, const float* __restrict__ g,
                             const float* __restrict__ be, float* __restrict__ bnc, int C)
{
  int c = threadIdx.x; if (c >= C) return;
  float a1=0.f, a2=0.f;
  for (int q=0;q<64;++q){ a1 += stats[q*256+c]; a2 += stats[q*256+128+c]; }
  float inv = 1.f/(float)ROWS;
  float mu = a1*inv; float var = a2*inv - mu*mu;
  float a = g[c]*rsqrtf(var + EPSBN);
  bnc[c] = a; bnc[128+c] = be[c] - mu*a;
}

// ================= conv2: bn1+relu on the fly, MFMA -> h2 + stats ==============
__global__ __launch_bounds__(256) void conv2_kernel(const bf16* __restrict__ h1,
                                                    const float* __restrict__ W1,
                                                    const float* __restrict__ b1,
                                                    const float* __restrict__ bnc,
                                                    bf16* __restrict__ h2,
                                                    float* __restrict__ stats)
{
  __shared__ __align__(16) bf16 As[64][72];
  __shared__ __align__(16) bf16 Bs[64][72];
  __shared__ float s1[C2], s2[C2];
  int t = threadIdx.x;
  int Rbase = blockIdx.x * 64;
  if (t < C2){ s1[t]=0.f; s2[t]=0.f; }
  {
    int o = t >> 2, q = t & 3;
    const float* wr = W1 + o*64 + q*16;
    bf16* bp = &Bs[o][q*16];
    #pragma unroll
    for (int v=0; v<4; ++v){
      float4 f = *(const float4*)(wr + v*4);
      bp[v*4+0]=(bf16)f.x; bp[v*4+1]=(bf16)f.y; bp[v*4+2]=(bf16)f.z; bp[v*4+3]=(bf16)f.w;
    }
  }
  {
    int r = t >> 2, q = t & 3;
    int R = Rbase + r;
    const bf16* hr = h1 + (size_t)R*64 + q*16;
    bfrag h0 = *(const bfrag*)hr;
    bfrag h1v = *(const bfrag*)(hr+8);
    #pragma unroll
    for (int j=0;j<8;++j){
      int c=q*16+j;
      As[r][c] = (bf16)fmaxf(fmaf(bnc[c], (float)h0[j], bnc[128+c]), 0.f);
    }
    #pragma unroll
    for (int j=0;j<8;++j){
      int c=q*16+8+j;
      As[r][c] = (bf16)fmaxf(fmaf(bnc[c], (float)h1v[j], bnc[128+c]), 0.f);
    }
  }
  __syncthreads();
  int wv = t >> 6, lane = t & 63;
  int row16 = wv * 16;
  int arow = lane & 15, kgrp = lane >> 4;
  ffrag acc[4] = {};
  #pragma unroll
  for (int kc = 0; kc < 2; ++kc){
    bfrag af = *(const bfrag*)&As[row16 + arow][kc*32 + kgrp*8];
    #pragma unroll
    for (int nt = 0; nt < 4; ++nt){
      bfrag bfv = *(const bfrag*)&Bs[nt*16 + arow][kc*32 + kgrp*8];
      acc[nt] = __builtin_amdgcn_mfma_f32_16x16x32_bf16(af, bfv, acc[nt], 0,0,0);
    }
  }
  #pragma unroll
  for (int nt=0; nt<4; ++nt){
    int c = nt*16 + arow;
    float bias = b1[c];
    float ls1=0.f, ls2=0.f;
    #pragma unroll
    for (int r=0;r<4;++r){
      float y = acc[nt][r] + bias;
      int grow = Rbase + row16 + kgrp*4 + r;
      h2[(size_t)grow*C2 + c] = (bf16)y;
      ls1 += y; ls2 += y*y;
    }
    ls1 += __shfl_xor(ls1, 16); ls1 += __shfl_xor(ls1, 32);
    ls2 += __shfl_xor(ls2, 16); ls2 += __shfl_xor(ls2, 32);
    if (kgrp==0){ atomicAdd(&s1[c], ls1); atomicAdd(&s2[c], ls2); }
  }
  __syncthreads();
  if (t < C2){
    float* gp = stats + (blockIdx.x & 63)*256;
    atomicAdd(&gp[t], s1[t]);
    atomicAdd(&gp[128 + t], s2[t]);
  }
}

// ========= conv3: bn2+relu, MFMA (N=128), in-block maxpool over k -> ymax ======
__global__ __launch_bounds__(256) void conv3_kernel(const bf16* __restrict__ h2,
                                                    const float* __restrict__ W2,
                                                    const float* __restrict__ b2,
                                                    const float* __restrict__ bnc,
                                                    float* __restrict__ ymax,
                                                    float* __restrict__ stats)
{
  __shared__ __align__(16) bf16 As[64][72];
  __shared__ __align__(16) bf16 Bs[128][72];
  __shared__ float s1[C3], s2[C3];
  __shared__ float wmax[4][C3];
  int t = threadIdx.x;
  int Rbase = blockIdx.x * 64;
  if (t < C3){ s1[t]=0.f; s2[t]=0.f; }
  {
    int o = t >> 1, q = t & 1;
    const float* wr = W2 + o*64 + q*32;
    bf16* bp = &Bs[o][q*32];
    #pragma unroll
    for (int v=0; v<8; ++v){
      float4 f = *(const float4*)(wr + v*4);
      bp[v*4+0]=(bf16)f.x; bp[v*4+1]=(bf16)f.y; bp[v*4+2]=(bf16)f.z; bp[v*4+3]=(bf16)f.w;
    }
  }
  {
    int r = t >> 2, q = t & 3;
    int R = Rbase + r;
    const bf16* hr = h2 + (size_t)R*64 + q*16;
    bfrag h0 = *(const bfrag*)hr;
    bfrag h1v = *(const bfrag*)(hr+8);
    #pragma unroll
    for (int j=0;j<8;++j){
      int c=q*16+j;
      As[r][c] = (bf16)fmaxf(fmaf(bnc[c], (float)h0[j], bnc[128+c]), 0.f);
    }
    #pragma unroll
    for (int j=0;j<8;++j){
      int c=q*16+8+j;
      As[r][c] = (bf16)fmaxf(fmaf(bnc[c], (float)h1v[j], bnc[128+c]), 0.f);
    }
  }
  __syncthreads();
  int wv = t >> 6, lane = t & 63;
  int row16 = wv * 16;
  int arow = lane & 15, kgrp = lane >> 4;
  ffrag acc[8] = {};
  #pragma unroll
  for (int kc = 0; kc < 2; ++kc){
    bfrag af = *(const bfrag*)&As[row16 + arow][kc*32 + kgrp*8];
    #pragma unroll
    for (int nt = 0; nt < 8; ++nt){
      bfrag bfv = *(const bfrag*)&Bs[nt*16 + arow][kc*32 + kgrp*8];
      acc[nt] = __builtin_amdgcn_mfma_f32_16x16x32_bf16(af, bfv, acc[nt], 0,0,0);
    }
  }
  #pragma unroll
  for (int nt=0; nt<8; ++nt){
    int c = nt*16 + arow;
    float bias = b2[c];
    float ls1=0.f, ls2=0.f, mm=-F_INF;
    #pragma unroll
    for (int r=0;r<4;++r){
      float y = acc[nt][r] + bias;
      ls1 += y; ls2 += y*y; mm = fmaxf(mm, y);
    }
    ls1 += __shfl_xor(ls1, 16); ls1 += __shfl_xor(ls1, 32);
    ls2 += __shfl_xor(ls2, 16); ls2 += __shfl_xor(ls2, 32);
    mm = fmaxf(mm, __shfl_xor(mm, 16)); mm = fmaxf(mm, __shfl_xor(mm, 32));
    if (kgrp==0){ atomicAdd(&s1[c], ls1); atomicAdd(&s2[c], ls2); wmax[wv][c]=mm; }
  }
  __syncthreads();
  {
    int half = t >> 7;
    int c = t & 127;
    float m = fmaxf(wmax[half*2][c], wmax[half*2+1][c]);
    ymax[(size_t)(blockIdx.x*2 + half)*C3 + c] = m;
  }
  if (t < C3){
    float* gp = stats + (blockIdx.x & 63)*256;
    atomicAdd(&gp[t], s1[t]);
    atomicAdd(&gp[128 + t], s2[t]);
  }
}

// ====== bn3+relu on pooled max (valid: a3>0), attention accumulators ===========
__global__ __launch_bounds__(256) void attprep_kernel(const float* __restrict__ ymax,
                                                      const float* __restrict__ bnc,
                                                      float* __restrict__ np0,
                                                      float* __restrict__ asum,
                                                      unsigned* __restrict__ amax)
{
  int i = blockIdx.x*256 + threadIdx.x;
  int c = i & 127; int bs = i >> 7; int b = bs >> 10; int s = bs & 1023;
  float v = fmaxf(fmaf(bnc[c], ymax[i], bnc[128+c]), 0.f);
  np0[i] = v;
  int slot = s & 7;
  atomicAdd(&asum[(slot*16 + b)*128 + c], v);
  atomicMax(&amax[(slot*16 + b)*128 + c], __float_as_uint(v));
}

// ================= channel attention (tiny) ====================================
__global__ __launch_bounds__(256) void attn_kernel(const float* __restrict__ asum,
                                                   const unsigned* __restrict__ amax,
                                                   const float* __restrict__ aW1,
                                                   const float* __restrict__ aW2,
                                                   float* __restrict__ scale)
{
  __shared__ float avg[16][128], mx[16][128], hA[16][16], hM[16][16];
  int t = threadIdx.x;
  for (int i=t; i<2048; i+=256){
    int b=i>>7, c=i&127;
    float s=0.f; unsigned m=0u;
    for (int q=0;q<8;++q){ s+=asum[(q*16+b)*128+c]; unsigned mm=amax[(q*16+b)*128+c]; m = mm>m?mm:m; }
    avg[b][c]=s*(1.f/1024.f); mx[b][c]=__uint_as_float(m);
  }
  __syncthreads();
  {
    int b=t>>4, r=t&15;
    float sa=0.f, sm=0.f;
    for (int c=0;c<128;++c){ float w=aW1[r*128+c]; sa+=w*avg[b][c]; sm+=w*mx[b][c]; }
    hA[b][r]=fmaxf(sa,0.f); hM[b][r]=fmaxf(sm,0.f);
  }
  __syncthreads();
  for (int i=t;i<2048;i+=256){
    int b=i>>7,c=i&127;
    float o=0.f;
    for (int r=0;r<16;++r){ o += aW2[c*16+r]*(hA[b][r]+hM[b][r]); }
    scale[i] = 1.f/(1.f+expf(-o));
  }
}

// ================= final scale + write =========================================
__global__ __launch_bounds__(256) void finout_kernel(const float* __restrict__ np0,
                                                     const float* __restrict__ scale,
                                                     float* __restrict__ out)
{
  int i = blockIdx.x*256 + threadIdx.x;
  int c = i & 127; int b = i >> 17;
  out[OUT_NP + i] = np0[i] * scale[b*128+c];
}

extern "C" void kernel_launch(void* const* d_in, const int* in_sizes, int n_in,
                              void* d_out, int out_size, void* d_ws, size_t ws_size,
                              hipStream_t stream)
{
  const float* xyz    = (const float*)d_in[0];
  const float* points = (const float*)d_in[1];
  const float* W0 = (const float*)d_in[2];
  const float* b0 = (const float*)d_in[3];
  const float* g0 = (const float*)d_in[4];
  const float* be0= (const float*)d_in[5];
  const float* W1 = (const float*)d_in[6];
  const float* b1 = (const float*)d_in[7];
  const float* g1 = (const float*)d_in[8];
  const float* be1= (const float*)d_in[9];
  const float* W2 = (const float*)d_in[10];
  const float* b2 = (const float*)d_in[11];
  const float* g2 = (const float*)d_in[12];
  const float* be2= (const float*)d_in[13];
  const float* aW1= (const float*)d_in[14];
  const float* aW2= (const float*)d_in[15];
  float* out = (float*)d_out;
  char* ws = (char*)d_ws;

  int*      fpsI  = (int*)(ws + OFF_FPS);
  float*    nxyz  = (float*)(ws + OFF_NXYZ);
  int*      knnI  = (int*)(ws + OFF_IDX);
  float*    stats = (float*)(ws + OFF_STATS);
  float*    asum  = (float*)(ws + OFF_ASUM);
  unsigned* amax  = (unsigned*)(ws + OFF_AMAX);
  float*    bnc   = (float*)(ws + OFF_BNC);
  float*    scl   = (float*)(ws + OFF_SCALE);
  float*    np0   = (float*)(ws + OFF_NP0);
  float*    ymax  = (float*)(ws + OFF_YMAX);
  bf16*     h1    = (bf16*)(ws + OFF_H1);
  bf16*     h2    = (bf16*)(ws + OFF_H2);

  hipMemsetAsync(ws + OFF_STATS, 0, ZERO_BYTES, stream);
  fps_kernel<<<BB, 256, 0, stream>>>(xyz, fpsI, nxyz, out);
  knn_kernel<<<BB*SS, 64, 0, stream>>>(xyz, nxyz, knnI);
  conv1_kernel<<<ROWS/64, 256, 0, stream>>>(xyz, points, W0, b0, nxyz, knnI, h1, stats);
  bnfin_kernel<<<1, 128, 0, stream>>>(stats, g0, be0, bnc, C1);
  conv2_kernel<<<ROWS/64, 256, 0, stream>>>(h1, W1, b1, bnc, h2, stats + 64*256);
  bnfin_kernel<<<1, 128, 0, stream>>>(stats + 64*256, g1, be1, bnc + 256, C2);
  conv3_kernel<<<ROWS/64, 256, 0, stream>>>(h2, W2, b2, bnc + 256, ymax, stats + 2*64*256);
  bnfin_kernel<<<1, 128, 0, stream>>>(stats + 2*64*256, g2, be2, bnc + 512, C3);
  attprep_kernel<<<(BB*SS*C3)/256, 256, 0, stream>>>(ymax, bnc + 512, np0, asum, amax);
  attn_kernel<<<1, 256, 0, stream>>>(asum, amax, aW1, aW2, scl);
  finout_kernel<<<(BB*SS*C3)/256, 256, 0, stream>>>(np0, scl, out);
}

// Round 2
// 1395.401 us; speedup vs baseline: 1.2652x; 1.2652x over previous
//
#include <hip/hip_runtime.h>
#include <hip/hip_bf16.h>

#define BB 16
#define NN 4096
#define SS 1024
#define KS 32
#define DF 64
#define INC 67
#define C1 64
#define C2 64
#define C3 128
#define ROWS (BB*SS*KS)      /* 524288 */
#define EPSBN 1e-5f
#define F_INF (__builtin_inff())

typedef __bf16 bf16;
typedef __bf16 bfrag __attribute__((ext_vector_type(8)));
typedef float  ffrag __attribute__((ext_vector_type(4)));
typedef unsigned long long u64;

// ---- output layout (floats) ----
#define OUT_NXYZ 0
#define OUT_NP   49152
#define OUT_FPS  2146304

// ---- workspace layout (bytes) ----
#define OFF_FPS   0u
#define OFF_NXYZ  65536u
#define OFF_IDX   262144u
#define OFF_STATS 2359296u     /* 3 layers x 64 slots x 256 floats = 196608 B */
#define OFF_ASUM  2555904u     /* 16*128 floats used (region 64KB) */
#define OFF_AMAX  2621440u
#define OFF_BNC   2686976u     /* 3 x 256 floats */
#define OFF_SCALE 2690048u
#define OFF_NP0   2698240u     /* 16384*128 f32 */
#define OFF_YMAX  11086848u    /* 16384*128 f32 */
#define OFF_H1    19475456u    /* 524288*64 bf16 */
#define OFF_H2    86584320u
#define ZERO_BYTES (196608u + 65536u + 65536u)

// ================= FPS =========================================================
// Bit-exact vs numpy: no FMA contraction, (dx^2+dy^2)+dz^2 order, argmax ties ->
// lowest index. One barrier/iter: double-buffered 16 candidate slots (u64 key =
// bits(d)<<32 | ~i, monotonic for d>=0), redundant tree-max by all threads.
__global__ __launch_bounds__(256) void fps_kernel(const float* __restrict__ xyz,
                                                  int* __restrict__ fps_i,
                                                  float* __restrict__ nxyz_ws,
                                                  float* __restrict__ out)
{
  __shared__ float lx[NN], ly[NN], lz[NN];
  __shared__ int lfps[SS];
  __shared__ u64 slotk[2][16];
  int b = blockIdx.x, t = threadIdx.x;
  const float* xb = xyz + (size_t)b*NN*3;
  for (int p = t; p < NN; p += 256){ lx[p]=xb[p*3]; ly[p]=xb[p*3+1]; lz[p]=xb[p*3+2]; }
  __syncthreads();
  float px[16],py[16],pz[16],pd[16];
  int p0 = t*16;
  #pragma unroll
  for (int j=0;j<16;++j){ px[j]=lx[p0+j]; py[j]=ly[p0+j]; pz[j]=lz[p0+j]; pd[j]=F_INF; }
  float cx = lx[NN/2], cy = ly[NN/2], cz = lz[NN/2];
  if (t==0) lfps[0]=NN/2;
  for (int it=1; it<SS; ++it){
    float bv=-1.f; int bi=p0;
    #pragma unroll
    for (int j=0;j<16;++j){
      float dx=px[j]-cx, dy=py[j]-cy, dz=pz[j]-cz;
      float d = __fadd_rn(__fadd_rn(__fmul_rn(dx,dx),__fmul_rn(dy,dy)),__fmul_rn(dz,dz));
      float nd = fminf(pd[j], d);
      pd[j]=nd;
      if (nd > bv){ bv=nd; bi=p0+j; }
    }
    u64 key = ((u64)__float_as_uint(bv) << 32) | (unsigned)(~bi);
    #pragma unroll
    for (int o=1;o<16;o<<=1){
      u64 k2 = __shfl_xor(key, o);
      key = (k2 > key) ? k2 : key;
    }
    int p = it & 1;
    if ((t & 15) == 0) slotk[p][t>>4] = key;
    __syncthreads();
    // redundant final reduce over 16 slots (broadcast reads, conflict-free)
    u64 v0 = slotk[p][0], v1 = slotk[p][1], v2 = slotk[p][2], v3 = slotk[p][3];
    u64 v4 = slotk[p][4], v5 = slotk[p][5], v6 = slotk[p][6], v7 = slotk[p][7];
    u64 v8 = slotk[p][8], v9 = slotk[p][9], va = slotk[p][10], vb = slotk[p][11];
    u64 vc = slotk[p][12], vd = slotk[p][13], ve = slotk[p][14], vf = slotk[p][15];
    v0 = v1 > v0 ? v1 : v0;  v2 = v3 > v2 ? v3 : v2;
    v4 = v5 > v4 ? v5 : v4;  v6 = v7 > v6 ? v7 : v6;
    v8 = v9 > v8 ? v9 : v8;  va = vb > va ? vb : va;
    vc = vd > vc ? vd : vc;  ve = vf > ve ? vf : ve;
    v0 = v2 > v0 ? v2 : v0;  v4 = v6 > v4 ? v6 : v4;
    v8 = va > v8 ? va : v8;  vc = ve > vc ? ve : vc;
    v0 = v4 > v0 ? v4 : v0;  v8 = vc > v8 ? vc : v8;
    v0 = v8 > v0 ? v8 : v0;
    int i = ~(unsigned)v0;
    cx = lx[i]; cy = ly[i]; cz = lz[i];
    if (t==0) lfps[it]=i;
  }
  __syncthreads();
  for (int s=t; s<SS; s+=256){
    int i = lfps[s];
    fps_i[b*SS+s]=i;
    out[OUT_FPS + b*SS + s] = (float)i;
    float xx=lx[i], yy=ly[i], zz=lz[i];
    int o3 = (b*SS+s)*3;
    out[OUT_NXYZ+o3]=xx; out[OUT_NXYZ+o3+1]=yy; out[OUT_NXYZ+o3+2]=zz;
    nxyz_ws[o3]=xx; nxyz_ws[o3+1]=yy; nxyz_ws[o3+2]=zz;
  }
}

// ================= kNN: 32 smallest dists per (b,s), ties -> lowest index ======
__global__ __launch_bounds__(64) void knn_kernel(const float* __restrict__ xyz,
                                                 const float* __restrict__ nxyz,
                                                 int* __restrict__ knn)
{
  __shared__ float ld[NN];
  int lane = threadIdx.x;
  int bs = blockIdx.x;
  int b = bs >> 10;
  const float* xb = xyz + (size_t)b*NN*3;
  float sx=nxyz[bs*3], sy=nxyz[bs*3+1], sz=nxyz[bs*3+2];
  float gv[8]; int gi[8];
  float lv = F_INF; int li = 0;
  #pragma unroll
  for (int g=0; g<8; ++g){
    float bgv = F_INF; int bgi = 0;
    #pragma unroll
    for (int jj=0; jj<8; ++jj){
      int p = (g*8+jj)*64 + lane;
      float dx=xb[p*3]-sx, dy=xb[p*3+1]-sy, dz=xb[p*3+2]-sz;
      float d = dx*dx+dy*dy+dz*dz;
      ld[p] = d;
      if (d < bgv){ bgv=d; bgi=p; }
    }
    gv[g]=bgv; gi[g]=bgi;
    if (bgv < lv){ lv=bgv; li=bgi; }
  }
  int kept = 0;
  for (int it=0; it<KS; ++it){
    float v=lv; int i=li;
    #pragma unroll
    for (int o=32;o;o>>=1){
      float v2=__shfl_xor(v,o); int i2=__shfl_xor(i,o);
      if (v2<v || (v2==v && i2<i)){ v=v2; i=i2; }
    }
    if (lane==it) kept = i;
    if ((i & 63) == lane){
      int j = i >> 6;
      ld[i] = F_INF;
      int g = j >> 3;
      float bgv=F_INF; int bgi=0;
      for (int jj=0;jj<8;++jj){
        int p = (g*8+jj)*64 + lane;
        float d = ld[p];
        if (d<bgv){bgv=d;bgi=p;}
      }
      #pragma unroll
      for (int q=0;q<8;++q){ if (q==g){ gv[q]=bgv; gi[q]=bgi; } }
      lv=F_INF; li=0;
      #pragma unroll
      for (int q=0;q<8;++q){ if (gv[q]<lv){ lv=gv[q]; li=gi[q]; } }
    }
  }
  if (lane < KS) knn[bs*KS + lane] = kept;
}

// ================= conv1: gather + MFMA (K=67 padded 96) -> h1 + stats =========
__global__ __launch_bounds__(256) void conv1_kernel(const float* __restrict__ xyz,
                                                    const float* __restrict__ points,
                                                    const float* __restrict__ W0,
                                                    const float* __restrict__ b0,
                                                    const float* __restrict__ nxyz,
                                                    const int* __restrict__ knn,
                                                    bf16* __restrict__ h1,
                                                    float* __restrict__ stats)
{
  __shared__ __align__(16) bf16 As[64][104];
  __shared__ __align__(16) bf16 Bs[64][104];
  __shared__ float s1[C1], s2[C1];
  int t = threadIdx.x;
  int Rbase = blockIdx.x * 64;
  if (t < C1){ s1[t]=0.f; s2[t]=0.f; }
  { // stage B (weights, channel-reordered: feat first, rel at 64..66, zeros to 95)
    int o = t >> 2, q = t & 3;
    const float* wr = W0 + o*INC;
    for (int cc = q*24; cc < q*24+24; ++cc){
      float w;
      if (cc < 64) w = wr[3+cc];
      else if (cc < 67) w = wr[cc-64];
      else w = 0.f;
      Bs[o][cc] = (bf16)w;
    }
  }
  { // stage A (gathered activations)
    int r = t >> 2, q = t & 3;
    int R = Rbase + r;
    int bs = R >> 5;
    int bIdx = bs >> 10;
    int nI = knn[R];
    const float* pr = points + ((size_t)(bIdx*NN + nI))*DF + q*16;
    float4 f0 = *(const float4*)(pr);
    float4 f1 = *(const float4*)(pr+4);
    float4 f2 = *(const float4*)(pr+8);
    float4 f3 = *(const float4*)(pr+12);
    bf16* ap = &As[r][q*16];
    ap[0]=(bf16)f0.x; ap[1]=(bf16)f0.y; ap[2]=(bf16)f0.z; ap[3]=(bf16)f0.w;
    ap[4]=(bf16)f1.x; ap[5]=(bf16)f1.y; ap[6]=(bf16)f1.z; ap[7]=(bf16)f1.w;
    ap[8]=(bf16)f2.x; ap[9]=(bf16)f2.y; ap[10]=(bf16)f2.z; ap[11]=(bf16)f2.w;
    ap[12]=(bf16)f3.x; ap[13]=(bf16)f3.y; ap[14]=(bf16)f3.z; ap[15]=(bf16)f3.w;
    if (q==0){
      const float* xr = xyz + ((size_t)(bIdx*NN + nI))*3;
      const float* nr = nxyz + bs*3;
      As[r][64]=(bf16)(xr[0]-nr[0]);
      As[r][65]=(bf16)(xr[1]-nr[1]);
      As[r][66]=(bf16)(xr[2]-nr[2]);
      for (int cc=67; cc<96; ++cc) As[r][cc]=(bf16)0.f;
    }
  }
  __syncthreads();
  int wv = t >> 6, lane = t & 63;
  int row16 = wv * 16;
  int arow = lane & 15, kgrp = lane >> 4;
  ffrag acc[4] = {};
  #pragma unroll
  for (int kc = 0; kc < 3; ++kc){
    bfrag af = *(const bfrag*)&As[row16 + arow][kc*32 + kgrp*8];
    #pragma unroll
    for (int nt = 0; nt < 4; ++nt){
      bfrag bfv = *(const bfrag*)&Bs[nt*16 + arow][kc*32 + kgrp*8];
      acc[nt] = __builtin_amdgcn_mfma_f32_16x16x32_bf16(af, bfv, acc[nt], 0,0,0);
    }
  }
  #pragma unroll
  for (int nt=0; nt<4; ++nt){
    int c = nt*16 + arow;
    float bias = b0[c];
    float ls1=0.f, ls2=0.f;
    #pragma unroll
    for (int r=0;r<4;++r){
      float y = acc[nt][r] + bias;
      int grow = Rbase + row16 + kgrp*4 + r;
      h1[(size_t)grow*C1 + c] = (bf16)y;
      ls1 += y; ls2 += y*y;
    }
    ls1 += __shfl_xor(ls1, 16); ls1 += __shfl_xor(ls1, 32);
    ls2 += __shfl_xor(ls2, 16); ls2 += __shfl_xor(ls2, 32);
    if (kgrp==0){ atomicAdd(&s1[c], ls1); atomicAdd(&s2[c], ls2); }
  }
  __syncthreads();
  if (t < C1){
    float* gp = stats + (blockIdx.x & 63)*256;
    atomicAdd(&gp[t], s1[t]);
    atomicAdd(&gp[128 + t], s2[t]);
  }
}

// ================= BN finalize -> affine coeffs ================================
__global__ void bnfin_kernel(const float* __restrict__ stats, const float* __restrict__ g,
                             const float* __restrict__ be, float* __restrict__ bnc, int C)
{
  int c = threadIdx.x; if (c >= C) return;
  float a1=0.f, a2=0.f;
  for (int q=0;q<64;++q){ a1 += stats[q*256+c]; a2 += stats[q*256+128+c]; }
  float inv = 1.f/(float)ROWS;
  float mu = a1*inv; float var = a2*inv - mu*mu;
  float a = g[c]*rsqrtf(var + EPSBN);
  bnc[c] = a; bnc[128+c] = be[c] - mu*a;
}

// ================= conv2: bn1+relu on the fly, MFMA -> h2 + stats ==============
__global__ __launch_bounds__(256) void conv2_kernel(const bf16* __restrict__ h1,
                                                    const float* __restrict__ W1,
                                                    const float* __restrict__ b1,
                                                    const float* __restrict__ bnc,
                                                    bf16* __restrict__ h2,
                                                    float* __restrict__ stats)
{
  __shared__ __align__(16) bf16 As[64][72];
  __shared__ __align__(16) bf16 Bs[64][72];
  __shared__ float s1[C2], s2[C2];
  int t = threadIdx.x;
  int Rbase = blockIdx.x * 64;
  if (t < C2){ s1[t]=0.f; s2[t]=0.f; }
  {
    int o = t >> 2, q = t & 3;
    const float* wr = W1 + o*64 + q*16;
    bf16* bp = &Bs[o][q*16];
    #pragma unroll
    for (int v=0; v<4; ++v){
      float4 f = *(const float4*)(wr + v*4);
      bp[v*4+0]=(bf16)f.x; bp[v*4+1]=(bf16)f.y; bp[v*4+2]=(bf16)f.z; bp[v*4+3]=(bf16)f.w;
    }
  }
  {
    int r = t >> 2, q = t & 3;
    int R = Rbase + r;
    const bf16* hr = h1 + (size_t)R*64 + q*16;
    bfrag h0 = *(const bfrag*)hr;
    bfrag h1v = *(const bfrag*)(hr+8);
    #pragma unroll
    for (int j=0;j<8;++j){
      int c=q*16+j;
      As[r][c] = (bf16)fmaxf(fmaf(bnc[c], (float)h0[j], bnc[128+c]), 0.f);
    }
    #pragma unroll
    for (int j=0;j<8;++j){
      int c=q*16+8+j;
      As[r][c] = (bf16)fmaxf(fmaf(bnc[c], (float)h1v[j], bnc[128+c]), 0.f);
    }
  }
  __syncthreads();
  int wv = t >> 6, lane = t & 63;
  int row16 = wv * 16;
  int arow = lane & 15, kgrp = lane >> 4;
  ffrag acc[4] = {};
  #pragma unroll
  for (int kc = 0; kc < 2; ++kc){
    bfrag af = *(const bfrag*)&As[row16 + arow][kc*32 + kgrp*8];
    #pragma unroll
    for (int nt = 0; nt < 4; ++nt){
      bfrag bfv = *(const bfrag*)&Bs[nt*16 + arow][kc*32 + kgrp*8];
      acc[nt] = __builtin_amdgcn_mfma_f32_16x16x32_bf16(af, bfv, acc[nt], 0,0,0);
    }
  }
  #pragma unroll
  for (int nt=0; nt<4; ++nt){
    int c = nt*16 + arow;
    float bias = b1[c];
    float ls1=0.f, ls2=0.f;
    #pragma unroll
    for (int r=0;r<4;++r){
      float y = acc[nt][r] + bias;
      int grow = Rbase + row16 + kgrp*4 + r;
      h2[(size_t)grow*C2 + c] = (bf16)y;
      ls1 += y; ls2 += y*y;
    }
    ls1 += __shfl_xor(ls1, 16); ls1 += __shfl_xor(ls1, 32);
    ls2 += __shfl_xor(ls2, 16); ls2 += __shfl_xor(ls2, 32);
    if (kgrp==0){ atomicAdd(&s1[c], ls1); atomicAdd(&s2[c], ls2); }
  }
  __syncthreads();
  if (t < C2){
    float* gp = stats + (blockIdx.x & 63)*256;
    atomicAdd(&gp[t], s1[t]);
    atomicAdd(&gp[128 + t], s2[t]);
  }
}

// ========= conv3: bn2+relu, MFMA (N=128), in-block maxpool over k -> ymax ======
__global__ __launch_bounds__(256) void conv3_kernel(const bf16* __restrict__ h2,
                                                    const float* __restrict__ W2,
                                                    const float* __restrict__ b2,
                                                    const float* __restrict__ bnc,
                                                    float* __restrict__ ymax,
                                                    float* __restrict__ stats)
{
  __shared__ __align__(16) bf16 As[64][72];
  __shared__ __align__(16) bf16 Bs[128][72];
  __shared__ float s1[C3], s2[C3];
  __shared__ float wmax[4][C3];
  int t = threadIdx.x;
  int Rbase = blockIdx.x * 64;
  if (t < C3){ s1[t]=0.f; s2[t]=0.f; }
  {
    int o = t >> 1, q = t & 1;
    const float* wr = W2 + o*64 + q*32;
    bf16* bp = &Bs[o][q*32];
    #pragma unroll
    for (int v=0; v<8; ++v){
      float4 f = *(const float4*)(wr + v*4);
      bp[v*4+0]=(bf16)f.x; bp[v*4+1]=(bf16)f.y; bp[v*4+2]=(bf16)f.z; bp[v*4+3]=(bf16)f.w;
    }
  }
  {
    int r = t >> 2, q = t & 3;
    int R = Rbase + r;
    const bf16* hr = h2 + (size_t)R*64 + q*16;
    bfrag h0 = *(const bfrag*)hr;
    bfrag h1v = *(const bfrag*)(hr+8);
    #pragma unroll
    for (int j=0;j<8;++j){
      int c=q*16+j;
      As[r][c] = (bf16)fmaxf(fmaf(bnc[c], (float)h0[j], bnc[128+c]), 0.f);
    }
    #pragma unroll
    for (int j=0;j<8;++j){
      int c=q*16+8+j;
      As[r][c] = (bf16)fmaxf(fmaf(bnc[c], (float)h1v[j], bnc[128+c]), 0.f);
    }
  }
  __syncthreads();
  int wv = t >> 6, lane = t & 63;
  int row16 = wv * 16;
  int arow = lane & 15, kgrp = lane >> 4;
  ffrag acc[8] = {};
  #pragma unroll
  for (int kc = 0; kc < 2; ++kc){
    bfrag af = *(const bfrag*)&As[row16 + arow][kc*32 + kgrp*8];
    #pragma unroll
    for (int nt = 0; nt < 8; ++nt){
      bfrag bfv = *(const bfrag*)&Bs[nt*16 + arow][kc*32 + kgrp*8];
      acc[nt] = __builtin_amdgcn_mfma_f32_16x16x32_bf16(af, bfv, acc[nt], 0,0,0);
    }
  }
  #pragma unroll
  for (int nt=0; nt<8; ++nt){
    int c = nt*16 + arow;
    float bias = b2[c];
    float ls1=0.f, ls2=0.f, mm=-F_INF;
    #pragma unroll
    for (int r=0;r<4;++r){
      float y = acc[nt][r] + bias;
      ls1 += y; ls2 += y*y; mm = fmaxf(mm, y);
    }
    ls1 += __shfl_xor(ls1, 16); ls1 += __shfl_xor(ls1, 32);
    ls2 += __shfl_xor(ls2, 16); ls2 += __shfl_xor(ls2, 32);
    mm = fmaxf(mm, __shfl_xor(mm, 16)); mm = fmaxf(mm, __shfl_xor(mm, 32));
    if (kgrp==0){ atomicAdd(&s1[c], ls1); atomicAdd(&s2[c], ls2); wmax[wv][c]=mm; }
  }
  __syncthreads();
  {
    int half = t >> 7;
    int c = t & 127;
    float m = fmaxf(wmax[half*2][c], wmax[half*2+1][c]);
    ymax[(size_t)(blockIdx.x*2 + half)*C3 + c] = m;
  }
  if (t < C3){
    float* gp = stats + (blockIdx.x & 63)*256;
    atomicAdd(&gp[t], s1[t]);
    atomicAdd(&gp[128 + t], s2[t]);
  }
}

// ====== bn3+relu on pooled max (valid: a3>0) -> np0 (elementwise only) =========
__global__ __launch_bounds__(256) void attprep_kernel(const float* __restrict__ ymax,
                                                      const float* __restrict__ bnc,
                                                      float* __restrict__ np0)
{
  int i = blockIdx.x*256 + threadIdx.x;
  int c = i & 127;
  np0[i] = fmaxf(fmaf(bnc[c], ymax[i], bnc[128+c]), 0.f);
}

// ====== coalesced avg/max reduction over S (replaces contended global atomics) =
__global__ __launch_bounds__(256) void attreduce_kernel(const float* __restrict__ np0,
                                                        float* __restrict__ asum,
                                                        unsigned* __restrict__ amax)
{
  __shared__ float rs[256], rm[256];
  int t = threadIdx.x;
  int b = blockIdx.x >> 3, sg = blockIdx.x & 7;
  int c = t & 127, h = t >> 7;
  const float* base = np0 + ((size_t)(b*1024 + sg*128 + h*64))*128 + c;
  float s = 0.f, m = 0.f;
  #pragma unroll 4
  for (int j=0;j<64;++j){
    float v = base[j*128];
    s += v; m = fmaxf(m, v);
  }
  rs[t]=s; rm[t]=m;
  __syncthreads();
  if (t < 128){
    float s2 = rs[t] + rs[t+128];
    float m2 = fmaxf(rm[t], rm[t+128]);
    atomicAdd(&asum[b*128+t], s2);
    atomicMax(&amax[b*128+t], __float_as_uint(m2));
  }
}

// ================= channel attention (tiny) ====================================
__global__ __launch_bounds__(256) void attn_kernel(const float* __restrict__ asum,
                                                   const unsigned* __restrict__ amax,
                                                   const float* __restrict__ aW1,
                                                   const float* __restrict__ aW2,
                                                   float* __restrict__ scale)
{
  __shared__ float avg[16][128], mx[16][128], hA[16][16], hM[16][16];
  int t = threadIdx.x;
  for (int i=t; i<2048; i+=256){
    int b=i>>7, c=i&127;
    avg[b][c]=asum[i]*(1.f/1024.f); mx[b][c]=__uint_as_float(amax[i]);
  }
  __syncthreads();
  {
    int b=t>>4, r=t&15;
    float sa=0.f, sm=0.f;
    for (int c=0;c<128;++c){ float w=aW1[r*128+c]; sa+=w*avg[b][c]; sm+=w*mx[b][c]; }
    hA[b][r]=fmaxf(sa,0.f); hM[b][r]=fmaxf(sm,0.f);
  }
  __syncthreads();
  for (int i=t;i<2048;i+=256){
    int b=i>>7,c=i&127;
    float o=0.f;
    for (int r=0;r<16;++r){ o += aW2[c*16+r]*(hA[b][r]+hM[b][r]); }
    scale[i] = 1.f/(1.f+expf(-o));
  }
}

// ================= final scale + write =========================================
__global__ __launch_bounds__(256) void finout_kernel(const float* __restrict__ np0,
                                                     const float* __restrict__ scale,
                                                     float* __restrict__ out)
{
  int i = blockIdx.x*256 + threadIdx.x;
  int c = i & 127; int b = i >> 17;
  out[OUT_NP + i] = np0[i] * scale[b*128+c];
}

extern "C" void kernel_launch(void* const* d_in, const int* in_sizes, int n_in,
                              void* d_out, int out_size, void* d_ws, size_t ws_size,
                              hipStream_t stream)
{
  const float* xyz    = (const float*)d_in[0];
  const float* points = (const float*)d_in[1];
  const float* W0 = (const float*)d_in[2];
  const float* b0 = (const float*)d_in[3];
  const float* g0 = (const float*)d_in[4];
  const float* be0= (const float*)d_in[5];
  const float* W1 = (const float*)d_in[6];
  const float* b1 = (const float*)d_in[7];
  const float* g1 = (const float*)d_in[8];
  const float* be1= (const float*)d_in[9];
  const float* W2 = (const float*)d_in[10];
  const float* b2 = (const float*)d_in[11];
  const float* g2 = (const float*)d_in[12];
  const float* be2= (const float*)d_in[13];
  const float* aW1= (const float*)d_in[14];
  const float* aW2= (const float*)d_in[15];
  float* out = (float*)d_out;
  char* ws = (char*)d_ws;

  int*      fpsI  = (int*)(ws + OFF_FPS);
  float*    nxyz  = (float*)(ws + OFF_NXYZ);
  int*      knnI  = (int*)(ws + OFF_IDX);
  float*    stats = (float*)(ws + OFF_STATS);
  float*    asum  = (float*)(ws + OFF_ASUM);
  unsigned* amax  = (unsigned*)(ws + OFF_AMAX);
  float*    bnc   = (float*)(ws + OFF_BNC);
  float*    scl   = (float*)(ws + OFF_SCALE);
  float*    np0   = (float*)(ws + OFF_NP0);
  float*    ymax  = (float*)(ws + OFF_YMAX);
  bf16*     h1    = (bf16*)(ws + OFF_H1);
  bf16*     h2    = (bf16*)(ws + OFF_H2);

  hipMemsetAsync(ws + OFF_STATS, 0, ZERO_BYTES, stream);
  fps_kernel<<<BB, 256, 0, stream>>>(xyz, fpsI, nxyz, out);
  knn_kernel<<<BB*SS, 64, 0, stream>>>(xyz, nxyz, knnI);
  conv1_kernel<<<ROWS/64, 256, 0, stream>>>(xyz, points, W0, b0, nxyz, knnI, h1, stats);
  bnfin_kernel<<<1, 128, 0, stream>>>(stats, g0, be0, bnc, C1);
  conv2_kernel<<<ROWS/64, 256, 0, stream>>>(h1, W1, b1, bnc, h2, stats + 64*256);
  bnfin_kernel<<<1, 128, 0, stream>>>(stats + 64*256, g1, be1, bnc + 256, C2);
  conv3_kernel<<<ROWS/64, 256, 0, stream>>>(h2, W2, b2, bnc + 256, ymax, stats + 2*64*256);
  bnfin_kernel<<<1, 128, 0, stream>>>(stats + 2*64*256, g2, be2, bnc + 512, C3);
  attprep_kernel<<<(BB*SS*C3)/256, 256, 0, stream>>>(ymax, bnc + 512, np0);
  attreduce_kernel<<<BB*8, 256, 0, stream>>>(np0, asum, amax);
  attn_kernel<<<1, 256, 0, stream>>>(asum, amax, aW1, aW2, scl);
  finout_kernel<<<(BB*SS*C3)/256, 256, 0, stream>>>(np0, scl, out);
}

// Round 3
// 1202.225 us; speedup vs baseline: 1.4685x; 1.1607x over previous
//
#include <hip/hip_runtime.h>
#include <hip/hip_bf16.h>

#define BB 16
#define NN 4096
#define SS 1024
#define KS 32
#define DF 64
#define INC 67
#define C1 64
#define C2 64
#define C3 128
#define ROWS (BB*SS*KS)      /* 524288 */
#define EPSBN 1e-5f
#define F_INF (__builtin_inff())

typedef __bf16 bf16;
typedef __bf16 bfrag __attribute__((ext_vector_type(8)));
typedef float  ffrag __attribute__((ext_vector_type(4)));
typedef unsigned long long u64;

// ---- output layout (floats) ----
#define OUT_NXYZ 0
#define OUT_NP   49152
#define OUT_FPS  2146304

// ---- workspace layout (bytes) ----
#define OFF_FPS   0u
#define OFF_NXYZ  65536u
#define OFF_IDX   262144u
#define OFF_STATS 2359296u     /* 3 layers x 64 slots x 256 floats = 196608 B */
#define OFF_ASUM  2555904u     /* 16*128 floats used (region 64KB) */
#define OFF_AMAX  2621440u
#define OFF_BNC   2686976u     /* 3 x 256 floats */
#define OFF_SCALE 2690048u
#define OFF_NP0   2698240u     /* 16384*128 f32 */
#define OFF_YMAX  11086848u    /* 16384*128 f32 */
#define OFF_H1    19475456u    /* 524288*64 bf16 */
#define OFF_H2    86584320u
#define ZERO_BYTES (196608u + 65536u + 65536u)

// 16-lane butterfly max via DPP row ops: xor masks {1,2,7,15} (quad_perm,
// quad_perm, row_half_mirror, row_mirror). ~2-4 cyc latency per step vs ~60
// for ds_bpermute-based __shfl_xor.
__device__ __forceinline__ u64 dpp_max16(u64 key){
  {
    int lo = __builtin_amdgcn_update_dpp((int)(unsigned)key, (int)(unsigned)key, 0xB1, 0xf, 0xf, true);
    int hi = __builtin_amdgcn_update_dpp((int)(key>>32), (int)(key>>32), 0xB1, 0xf, 0xf, true);
    u64 k2 = ((u64)(unsigned)hi<<32)|(unsigned)lo;
    key = k2 > key ? k2 : key;
  }
  {
    int lo = __builtin_amdgcn_update_dpp((int)(unsigned)key, (int)(unsigned)key, 0x4E, 0xf, 0xf, true);
    int hi = __builtin_amdgcn_update_dpp((int)(key>>32), (int)(key>>32), 0x4E, 0xf, 0xf, true);
    u64 k2 = ((u64)(unsigned)hi<<32)|(unsigned)lo;
    key = k2 > key ? k2 : key;
  }
  {
    int lo = __builtin_amdgcn_update_dpp((int)(unsigned)key, (int)(unsigned)key, 0x141, 0xf, 0xf, true);
    int hi = __builtin_amdgcn_update_dpp((int)(key>>32), (int)(key>>32), 0x141, 0xf, 0xf, true);
    u64 k2 = ((u64)(unsigned)hi<<32)|(unsigned)lo;
    key = k2 > key ? k2 : key;
  }
  {
    int lo = __builtin_amdgcn_update_dpp((int)(unsigned)key, (int)(unsigned)key, 0x140, 0xf, 0xf, true);
    int hi = __builtin_amdgcn_update_dpp((int)(key>>32), (int)(key>>32), 0x140, 0xf, 0xf, true);
    u64 k2 = ((u64)(unsigned)hi<<32)|(unsigned)lo;
    key = k2 > key ? k2 : key;
  }
  return key;
}

// ================= FPS =========================================================
// Bit-exact vs numpy: no FMA contraction, (dx^2+dy^2)+dz^2 order, argmax ties ->
// lowest index (u64 key = bits(d)<<32 | ~i, monotonic for d>=0). One barrier per
// iter, double-buffered slots; DPP butterfly for both reduce phases.
__global__ __launch_bounds__(256) void fps_kernel(const float* __restrict__ xyz,
                                                  int* __restrict__ fps_i,
                                                  float* __restrict__ nxyz_ws,
                                                  float* __restrict__ out)
{
  __shared__ float lx[NN], ly[NN], lz[NN];
  __shared__ int lfps[SS];
  __shared__ u64 slotk[2][16];
  int b = blockIdx.x, t = threadIdx.x;
  const float* xb = xyz + (size_t)b*NN*3;
  for (int p = t; p < NN; p += 256){ lx[p]=xb[p*3]; ly[p]=xb[p*3+1]; lz[p]=xb[p*3+2]; }
  __syncthreads();
  float px[16],py[16],pz[16],pd[16];
  int p0 = t*16;
  #pragma unroll
  for (int j=0;j<16;++j){ px[j]=lx[p0+j]; py[j]=ly[p0+j]; pz[j]=lz[p0+j]; pd[j]=F_INF; }
  float cx = lx[NN/2], cy = ly[NN/2], cz = lz[NN/2];
  if (t==0) lfps[0]=NN/2;
  for (int it=1; it<SS; ++it){
    float bv=-1.f; int bi=p0;
    #pragma unroll
    for (int j=0;j<16;++j){
      float dx=px[j]-cx, dy=py[j]-cy, dz=pz[j]-cz;
      float d = __fadd_rn(__fadd_rn(__fmul_rn(dx,dx),__fmul_rn(dy,dy)),__fmul_rn(dz,dz));
      float nd = fminf(pd[j], d);
      pd[j]=nd;
      if (nd > bv){ bv=nd; bi=p0+j; }
    }
    u64 key = ((u64)__float_as_uint(bv) << 32) | (unsigned)(~bi);
    key = dpp_max16(key);
    int p = it & 1;
    if ((t & 15) == 0) slotk[p][t>>4] = key;
    __syncthreads();
    // each lane reads one slot (16 addrs x 4-way broadcast, conflict-free),
    // second DPP butterfly -> every lane holds the global max key
    u64 k = slotk[p][t & 15];
    k = dpp_max16(k);
    int i = ~(unsigned)k;
    cx = lx[i]; cy = ly[i]; cz = lz[i];
    if (t==0) lfps[it]=i;
  }
  __syncthreads();
  for (int s=t; s<SS; s+=256){
    int i = lfps[s];
    fps_i[b*SS+s]=i;
    out[OUT_FPS + b*SS + s] = (float)i;
    float xx=lx[i], yy=ly[i], zz=lz[i];
    int o3 = (b*SS+s)*3;
    out[OUT_NXYZ+o3]=xx; out[OUT_NXYZ+o3+1]=yy; out[OUT_NXYZ+o3+2]=zz;
    nxyz_ws[o3]=xx; nxyz_ws[o3+1]=yy; nxyz_ws[o3+2]=zz;
  }
}

// ================= kNN: 32 smallest dists per (b,s), ties -> lowest index ======
__global__ __launch_bounds__(64) void knn_kernel(const float* __restrict__ xyz,
                                                 const float* __restrict__ nxyz,
                                                 int* __restrict__ knn)
{
  __shared__ float ld[NN];
  int lane = threadIdx.x;
  int bs = blockIdx.x;
  int b = bs >> 10;
  const float* xb = xyz + (size_t)b*NN*3;
  float sx=nxyz[bs*3], sy=nxyz[bs*3+1], sz=nxyz[bs*3+2];
  float gv[8]; int gi[8];
  float lv = F_INF; int li = 0;
  #pragma unroll
  for (int g=0; g<8; ++g){
    float bgv = F_INF; int bgi = 0;
    #pragma unroll
    for (int jj=0; jj<8; ++jj){
      int p = (g*8+jj)*64 + lane;
      float dx=xb[p*3]-sx, dy=xb[p*3+1]-sy, dz=xb[p*3+2]-sz;
      float d = dx*dx+dy*dy+dz*dz;
      ld[p] = d;
      if (d < bgv){ bgv=d; bgi=p; }
    }
    gv[g]=bgv; gi[g]=bgi;
    if (bgv < lv){ lv=bgv; li=bgi; }
  }
  int kept = 0;
  for (int it=0; it<KS; ++it){
    float v=lv; int i=li;
    #pragma unroll
    for (int o=32;o;o>>=1){
      float v2=__shfl_xor(v,o); int i2=__shfl_xor(i,o);
      if (v2<v || (v2==v && i2<i)){ v=v2; i=i2; }
    }
    if (lane==it) kept = i;
    if ((i & 63) == lane){
      int j = i >> 6;
      ld[i] = F_INF;
      int g = j >> 3;
      float bgv=F_INF; int bgi=0;
      for (int jj=0;jj<8;++jj){
        int p = (g*8+jj)*64 + lane;
        float d = ld[p];
        if (d<bgv){bgv=d;bgi=p;}
      }
      #pragma unroll
      for (int q=0;q<8;++q){ if (q==g){ gv[q]=bgv; gi[q]=bgi; } }
      lv=F_INF; li=0;
      #pragma unroll
      for (int q=0;q<8;++q){ if (gv[q]<lv){ lv=gv[q]; li=gi[q]; } }
    }
  }
  if (lane < KS) knn[bs*KS + lane] = kept;
}

// ================= conv1: gather + MFMA (K=67 padded 96) -> h1 + stats =========
__global__ __launch_bounds__(256) void conv1_kernel(const float* __restrict__ xyz,
                                                    const float* __restrict__ points,
                                                    const float* __restrict__ W0,
                                                    const float* __restrict__ b0,
                                                    const float* __restrict__ nxyz,
                                                    const int* __restrict__ knn,
                                                    bf16* __restrict__ h1,
                                                    float* __restrict__ stats)
{
  __shared__ __align__(16) bf16 As[64][104];
  __shared__ __align__(16) bf16 Bs[64][104];
  __shared__ float s1[C1], s2[C1];
  int t = threadIdx.x;
  int Rbase = blockIdx.x * 64;
  if (t < C1){ s1[t]=0.f; s2[t]=0.f; }
  { // stage B (weights, channel-reordered: feat first, rel at 64..66, zeros to 95)
    int o = t >> 2, q = t & 3;
    const float* wr = W0 + o*INC;
    for (int cc = q*24; cc < q*24+24; ++cc){
      float w;
      if (cc < 64) w = wr[3+cc];
      else if (cc < 67) w = wr[cc-64];
      else w = 0.f;
      Bs[o][cc] = (bf16)w;
    }
  }
  { // stage A (gathered activations)
    int r = t >> 2, q = t & 3;
    int R = Rbase + r;
    int bs = R >> 5;
    int bIdx = bs >> 10;
    int nI = knn[R];
    const float* pr = points + ((size_t)(bIdx*NN + nI))*DF + q*16;
    float4 f0 = *(const float4*)(pr);
    float4 f1 = *(const float4*)(pr+4);
    float4 f2 = *(const float4*)(pr+8);
    float4 f3 = *(const float4*)(pr+12);
    bf16* ap = &As[r][q*16];
    ap[0]=(bf16)f0.x; ap[1]=(bf16)f0.y; ap[2]=(bf16)f0.z; ap[3]=(bf16)f0.w;
    ap[4]=(bf16)f1.x; ap[5]=(bf16)f1.y; ap[6]=(bf16)f1.z; ap[7]=(bf16)f1.w;
    ap[8]=(bf16)f2.x; ap[9]=(bf16)f2.y; ap[10]=(bf16)f2.z; ap[11]=(bf16)f2.w;
    ap[12]=(bf16)f3.x; ap[13]=(bf16)f3.y; ap[14]=(bf16)f3.z; ap[15]=(bf16)f3.w;
    if (q==0){
      const float* xr = xyz + ((size_t)(bIdx*NN + nI))*3;
      const float* nr = nxyz + bs*3;
      As[r][64]=(bf16)(xr[0]-nr[0]);
      As[r][65]=(bf16)(xr[1]-nr[1]);
      As[r][66]=(bf16)(xr[2]-nr[2]);
      for (int cc=67; cc<96; ++cc) As[r][cc]=(bf16)0.f;
    }
  }
  __syncthreads();
  int wv = t >> 6, lane = t & 63;
  int row16 = wv * 16;
  int arow = lane & 15, kgrp = lane >> 4;
  ffrag acc[4] = {};
  #pragma unroll
  for (int kc = 0; kc < 3; ++kc){
    bfrag af = *(const bfrag*)&As[row16 + arow][kc*32 + kgrp*8];
    #pragma unroll
    for (int nt = 0; nt < 4; ++nt){
      bfrag bfv = *(const bfrag*)&Bs[nt*16 + arow][kc*32 + kgrp*8];
      acc[nt] = __builtin_amdgcn_mfma_f32_16x16x32_bf16(af, bfv, acc[nt], 0,0,0);
    }
  }
  #pragma unroll
  for (int nt=0; nt<4; ++nt){
    int c = nt*16 + arow;
    float bias = b0[c];
    float ls1=0.f, ls2=0.f;
    #pragma unroll
    for (int r=0;r<4;++r){
      float y = acc[nt][r] + bias;
      int grow = Rbase + row16 + kgrp*4 + r;
      h1[(size_t)grow*C1 + c] = (bf16)y;
      ls1 += y; ls2 += y*y;
    }
    ls1 += __shfl_xor(ls1, 16); ls1 += __shfl_xor(ls1, 32);
    ls2 += __shfl_xor(ls2, 16); ls2 += __shfl_xor(ls2, 32);
    if (kgrp==0){ atomicAdd(&s1[c], ls1); atomicAdd(&s2[c], ls2); }
  }
  __syncthreads();
  if (t < C1){
    float* gp = stats + (blockIdx.x & 63)*256;
    atomicAdd(&gp[t], s1[t]);
    atomicAdd(&gp[128 + t], s2[t]);
  }
}

// ================= BN finalize -> affine coeffs ================================
__global__ void bnfin_kernel(const float* __restrict__ stats, const float* __restrict__ g,
                             const float* __restrict__ be, float* __restrict__ bnc, int C)
{
  int c = threadIdx.x; if (c >= C) return;
  float a1=0.f, a2=0.f;
  for (int q=0;q<64;++q){ a1 += stats[q*256+c]; a2 += stats[q*256+128+c]; }
  float inv = 1.f/(float)ROWS;
  float mu = a1*inv; float var = a2*inv - mu*mu;
  float a = g[c]*rsqrtf(var + EPSBN);
  bnc[c] = a; bnc[128+c] = be[c] - mu*a;
}

// ================= conv2: bn1+relu on the fly, MFMA -> h2 + stats ==============
__global__ __launch_bounds__(256) void conv2_kernel(const bf16* __restrict__ h1,
                                                    const float* __restrict__ W1,
                                                    const float* __restrict__ b1,
                                                    const float* __restrict__ bnc,
                                                    bf16* __restrict__ h2,
                                                    float* __restrict__ stats)
{
  __shared__ __align__(16) bf16 As[64][72];
  __shared__ __align__(16) bf16 Bs[64][72];
  __shared__ float s1[C2], s2[C2];
  int t = threadIdx.x;
  int Rbase = blockIdx.x * 64;
  if (t < C2){ s1[t]=0.f; s2[t]=0.f; }
  {
    int o = t >> 2, q = t & 3;
    const float* wr = W1 + o*64 + q*16;
    bf16* bp = &Bs[o][q*16];
    #pragma unroll
    for (int v=0; v<4; ++v){
      float4 f = *(const float4*)(wr + v*4);
      bp[v*4+0]=(bf16)f.x; bp[v*4+1]=(bf16)f.y; bp[v*4+2]=(bf16)f.z; bp[v*4+3]=(bf16)f.w;
    }
  }
  {
    int r = t >> 2, q = t & 3;
    int R = Rbase + r;
    const bf16* hr = h1 + (size_t)R*64 + q*16;
    bfrag h0 = *(const bfrag*)hr;
    bfrag h1v = *(const bfrag*)(hr+8);
    #pragma unroll
    for (int j=0;j<8;++j){
      int c=q*16+j;
      As[r][c] = (bf16)fmaxf(fmaf(bnc[c], (float)h0[j], bnc[128+c]), 0.f);
    }
    #pragma unroll
    for (int j=0;j<8;++j){
      int c=q*16+8+j;
      As[r][c] = (bf16)fmaxf(fmaf(bnc[c], (float)h1v[j], bnc[128+c]), 0.f);
    }
  }
  __syncthreads();
  int wv = t >> 6, lane = t & 63;
  int row16 = wv * 16;
  int arow = lane & 15, kgrp = lane >> 4;
  ffrag acc[4] = {};
  #pragma unroll
  for (int kc = 0; kc < 2; ++kc){
    bfrag af = *(const bfrag*)&As[row16 + arow][kc*32 + kgrp*8];
    #pragma unroll
    for (int nt = 0; nt < 4; ++nt){
      bfrag bfv = *(const bfrag*)&Bs[nt*16 + arow][kc*32 + kgrp*8];
      acc[nt] = __builtin_amdgcn_mfma_f32_16x16x32_bf16(af, bfv, acc[nt], 0,0,0);
    }
  }
  #pragma unroll
  for (int nt=0; nt<4; ++nt){
    int c = nt*16 + arow;
    float bias = b1[c];
    float ls1=0.f, ls2=0.f;
    #pragma unroll
    for (int r=0;r<4;++r){
      float y = acc[nt][r] + bias;
      int grow = Rbase + row16 + kgrp*4 + r;
      h2[(size_t)grow*C2 + c] = (bf16)y;
      ls1 += y; ls2 += y*y;
    }
    ls1 += __shfl_xor(ls1, 16); ls1 += __shfl_xor(ls1, 32);
    ls2 += __shfl_xor(ls2, 16); ls2 += __shfl_xor(ls2, 32);
    if (kgrp==0){ atomicAdd(&s1[c], ls1); atomicAdd(&s2[c], ls2); }
  }
  __syncthreads();
  if (t < C2){
    float* gp = stats + (blockIdx.x & 63)*256;
    atomicAdd(&gp[t], s1[t]);
    atomicAdd(&gp[128 + t], s2[t]);
  }
}

// ========= conv3: bn2+relu, MFMA (N=128), in-block maxpool over k -> ymax ======
__global__ __launch_bounds__(256) void conv3_kernel(const bf16* __restrict__ h2,
                                                    const float* __restrict__ W2,
                                                    const float* __restrict__ b2,
                                                    const float* __restrict__ bnc,
                                                    float* __restrict__ ymax,
                                                    float* __restrict__ stats)
{
  __shared__ __align__(16) bf16 As[64][72];
  __shared__ __align__(16) bf16 Bs[128][72];
  __shared__ float s1[C3], s2[C3];
  __shared__ float wmax[4][C3];
  int t = threadIdx.x;
  int Rbase = blockIdx.x * 64;
  if (t < C3){ s1[t]=0.f; s2[t]=0.f; }
  {
    int o = t >> 1, q = t & 1;
    const float* wr = W2 + o*64 + q*32;
    bf16* bp = &Bs[o][q*32];
    #pragma unroll
    for (int v=0; v<8; ++v){
      float4 f = *(const float4*)(wr + v*4);
      bp[v*4+0]=(bf16)f.x; bp[v*4+1]=(bf16)f.y; bp[v*4+2]=(bf16)f.z; bp[v*4+3]=(bf16)f.w;
    }
  }
  {
    int r = t >> 2, q = t & 3;
    int R = Rbase + r;
    const bf16* hr = h2 + (size_t)R*64 + q*16;
    bfrag h0 = *(const bfrag*)hr;
    bfrag h1v = *(const bfrag*)(hr+8);
    #pragma unroll
    for (int j=0;j<8;++j){
      int c=q*16+j;
      As[r][c] = (bf16)fmaxf(fmaf(bnc[c], (float)h0[j], bnc[128+c]), 0.f);
    }
    #pragma unroll
    for (int j=0;j<8;++j){
      int c=q*16+8+j;
      As[r][c] = (bf16)fmaxf(fmaf(bnc[c], (float)h1v[j], bnc[128+c]), 0.f);
    }
  }
  __syncthreads();
  int wv = t >> 6, lane = t & 63;
  int row16 = wv * 16;
  int arow = lane & 15, kgrp = lane >> 4;
  ffrag acc[8] = {};
  #pragma unroll
  for (int kc = 0; kc < 2; ++kc){
    bfrag af = *(const bfrag*)&As[row16 + arow][kc*32 + kgrp*8];
    #pragma unroll
    for (int nt = 0; nt < 8; ++nt){
      bfrag bfv = *(const bfrag*)&Bs[nt*16 + arow][kc*32 + kgrp*8];
      acc[nt] = __builtin_amdgcn_mfma_f32_16x16x32_bf16(af, bfv, acc[nt], 0,0,0);
    }
  }
  #pragma unroll
  for (int nt=0; nt<8; ++nt){
    int c = nt*16 + arow;
    float bias = b2[c];
    float ls1=0.f, ls2=0.f, mm=-F_INF;
    #pragma unroll
    for (int r=0;r<4;++r){
      float y = acc[nt][r] + bias;
      ls1 += y; ls2 += y*y; mm = fmaxf(mm, y);
    }
    ls1 += __shfl_xor(ls1, 16); ls1 += __shfl_xor(ls1, 32);
    ls2 += __shfl_xor(ls2, 16); ls2 += __shfl_xor(ls2, 32);
    mm = fmaxf(mm, __shfl_xor(mm, 16)); mm = fmaxf(mm, __shfl_xor(mm, 32));
    if (kgrp==0){ atomicAdd(&s1[c], ls1); atomicAdd(&s2[c], ls2); wmax[wv][c]=mm; }
  }
  __syncthreads();
  {
    int half = t >> 7;
    int c = t & 127;
    float m = fmaxf(wmax[half*2][c], wmax[half*2+1][c]);
    ymax[(size_t)(blockIdx.x*2 + half)*C3 + c] = m;
  }
  if (t < C3){
    float* gp = stats + (blockIdx.x & 63)*256;
    atomicAdd(&gp[t], s1[t]);
    atomicAdd(&gp[128 + t], s2[t]);
  }
}

// === bn3+relu (valid: a3>0) + np0 write + avg/max reduction, fused =============
__global__ __launch_bounds__(256) void attreduce_kernel(const float* __restrict__ ymax,
                                                        const float* __restrict__ bnc,
                                                        float* __restrict__ np0,
                                                        float* __restrict__ asum,
                                                        unsigned* __restrict__ amax)
{
  __shared__ float rs[256], rm[256];
  int t = threadIdx.x;
  int b = blockIdx.x >> 3, sg = blockIdx.x & 7;
  int c = t & 127, h = t >> 7;
  float a = bnc[c], bb = bnc[128+c];
  size_t base = ((size_t)(b*1024 + sg*128 + h*64))*128 + c;
  float s = 0.f, m = 0.f;
  #pragma unroll 4
  for (int j=0;j<64;++j){
    float v = fmaxf(fmaf(a, ymax[base + (size_t)j*128], bb), 0.f);
    np0[base + (size_t)j*128] = v;
    s += v; m = fmaxf(m, v);
  }
  rs[t]=s; rm[t]=m;
  __syncthreads();
  if (t < 128){
    float s2 = rs[t] + rs[t+128];
    float m2 = fmaxf(rm[t], rm[t+128]);
    atomicAdd(&asum[b*128+t], s2);
    atomicMax(&amax[b*128+t], __float_as_uint(m2));
  }
}

// ================= channel attention (tiny) ====================================
__global__ __launch_bounds__(256) void attn_kernel(const float* __restrict__ asum,
                                                   const unsigned* __restrict__ amax,
                                                   const float* __restrict__ aW1,
                                                   const float* __restrict__ aW2,
                                                   float* __restrict__ scale)
{
  __shared__ float avg[16][128], mx[16][128], hA[16][16], hM[16][16];
  int t = threadIdx.x;
  for (int i=t; i<2048; i+=256){
    int b=i>>7, c=i&127;
    avg[b][c]=asum[i]*(1.f/1024.f); mx[b][c]=__uint_as_float(amax[i]);
  }
  __syncthreads();
  {
    int b=t>>4, r=t&15;
    float sa=0.f, sm=0.f;
    for (int c=0;c<128;++c){ float w=aW1[r*128+c]; sa+=w*avg[b][c]; sm+=w*mx[b][c]; }
    hA[b][r]=fmaxf(sa,0.f); hM[b][r]=fmaxf(sm,0.f);
  }
  __syncthreads();
  for (int i=t;i<2048;i+=256){
    int b=i>>7,c=i&127;
    float o=0.f;
    for (int r=0;r<16;++r){ o += aW2[c*16+r]*(hA[b][r]+hM[b][r]); }
    scale[i] = 1.f/(1.f+expf(-o));
  }
}

// ================= final scale + write =========================================
__global__ __launch_bounds__(256) void finout_kernel(const float* __restrict__ np0,
                                                     const float* __restrict__ scale,
                                                     float* __restrict__ out)
{
  int i = blockIdx.x*256 + threadIdx.x;
  int c = i & 127; int b = i >> 17;
  out[OUT_NP + i] = np0[i] * scale[b*128+c];
}

extern "C" void kernel_launch(void* const* d_in, const int* in_sizes, int n_in,
                              void* d_out, int out_size, void* d_ws, size_t ws_size,
                              hipStream_t stream)
{
  const float* xyz    = (const float*)d_in[0];
  const float* points = (const float*)d_in[1];
  const float* W0 = (const float*)d_in[2];
  const float* b0 = (const float*)d_in[3];
  const float* g0 = (const float*)d_in[4];
  const float* be0= (const float*)d_in[5];
  const float* W1 = (const float*)d_in[6];
  const float* b1 = (const float*)d_in[7];
  const float* g1 = (const float*)d_in[8];
  const float* be1= (const float*)d_in[9];
  const float* W2 = (const float*)d_in[10];
  const float* b2 = (const float*)d_in[11];
  const float* g2 = (const float*)d_in[12];
  const float* be2= (const float*)d_in[13];
  const float* aW1= (const float*)d_in[14];
  const float* aW2= (const float*)d_in[15];
  float* out = (float*)d_out;
  char* ws = (char*)d_ws;

  int*      fpsI  = (int*)(ws + OFF_FPS);
  float*    nxyz  = (float*)(ws + OFF_NXYZ);
  int*      knnI  = (int*)(ws + OFF_IDX);
  float*    stats = (float*)(ws + OFF_STATS);
  float*    asum  = (float*)(ws + OFF_ASUM);
  unsigned* amax  = (unsigned*)(ws + OFF_AMAX);
  float*    bnc   = (float*)(ws + OFF_BNC);
  float*    scl   = (float*)(ws + OFF_SCALE);
  float*    np0   = (float*)(ws + OFF_NP0);
  float*    ymax  = (float*)(ws + OFF_YMAX);
  bf16*     h1    = (bf16*)(ws + OFF_H1);
  bf16*     h2    = (bf16*)(ws + OFF_H2);

  hipMemsetAsync(ws + OFF_STATS, 0, ZERO_BYTES, stream);
  fps_kernel<<<BB, 256, 0, stream>>>(xyz, fpsI, nxyz, out);
  knn_kernel<<<BB*SS, 64, 0, stream>>>(xyz, nxyz, knnI);
  conv1_kernel<<<ROWS/64, 256, 0, stream>>>(xyz, points, W0, b0, nxyz, knnI, h1, stats);
  bnfin_kernel<<<1, 128, 0, stream>>>(stats, g0, be0, bnc, C1);
  conv2_kernel<<<ROWS/64, 256, 0, stream>>>(h1, W1, b1, bnc, h2, stats + 64*256);
  bnfin_kernel<<<1, 128, 0, stream>>>(stats + 64*256, g1, be1, bnc + 256, C2);
  conv3_kernel<<<ROWS/64, 256, 0, stream>>>(h2, W2, b2, bnc + 256, ymax, stats + 2*64*256);
  bnfin_kernel<<<1, 128, 0, stream>>>(stats + 2*64*256, g2, be2, bnc + 512, C3);
  attreduce_kernel<<<BB*8, 256, 0, stream>>>(ymax, bnc + 512, np0, asum, amax);
  attn_kernel<<<1, 256, 0, stream>>>(asum, amax, aW1, aW2, scl);
  finout_kernel<<<(BB*SS*C3)/256, 256, 0, stream>>>(np0, scl, out);
}

// Round 4
// 1087.216 us; speedup vs baseline: 1.6238x; 1.1058x over previous
//
#include <hip/hip_runtime.h>
#include <hip/hip_bf16.h>

#define BB 16
#define NN 4096
#define SS 1024
#define KS 32
#define DF 64
#define INC 67
#define C1 64
#define C2 64
#define C3 128
#define ROWS (BB*SS*KS)      /* 524288 */
#define EPSBN 1e-5f
#define F_INF (__builtin_inff())

typedef __bf16 bf16;
typedef __bf16 bfrag __attribute__((ext_vector_type(8)));
typedef float  ffrag __attribute__((ext_vector_type(4)));
typedef float  f2    __attribute__((ext_vector_type(2)));
typedef unsigned long long u64;

// ---- output layout (floats) ----
#define OUT_NXYZ 0
#define OUT_NP   49152
#define OUT_FPS  2146304

// ---- workspace layout (bytes) ----
#define OFF_FPS   0u
#define OFF_NXYZ  65536u
#define OFF_IDX   262144u
#define OFF_STATS 2359296u     /* 3 layers x 64 slots x 256 floats = 196608 B */
#define OFF_ASUM  2555904u
#define OFF_AMAX  2621440u
#define OFF_BNC   2686976u
#define OFF_SCALE 2690048u
#define OFF_NP0   2698240u     /* 16384*128 f32 */
#define OFF_YMAX  11086848u    /* 16384*128 f32 */
#define OFF_H1    19475456u    /* 524288*64 bf16 */
#define OFF_H2    86584320u
#define ZERO_BYTES (196608u + 65536u + 65536u)

// u64 max combine via one dpp step (both halves move identically)
#define DPP_MAX_STEP(k, ctrl, rmask, bc) { \
  int _lo = __builtin_amdgcn_update_dpp(0, (int)(unsigned)(k), (ctrl), (rmask), 0xf, (bc)); \
  int _hi = __builtin_amdgcn_update_dpp(0, (int)((k)>>32),     (ctrl), (rmask), 0xf, (bc)); \
  u64 _k2 = ((u64)(unsigned)_hi << 32) | (unsigned)_lo; \
  if (_k2 > (k)) (k) = _k2; }

// full wave64 max-reduce -> lane 63 holds result (GCN row_shr/row_bcast pattern)
__device__ __forceinline__ u64 dpp_wavemax64(u64 k){
  DPP_MAX_STEP(k, 0x111, 0xf, true)   // row_shr:1
  DPP_MAX_STEP(k, 0x112, 0xf, true)   // row_shr:2
  DPP_MAX_STEP(k, 0x114, 0xf, true)   // row_shr:4
  DPP_MAX_STEP(k, 0x118, 0xf, true)   // row_shr:8
  DPP_MAX_STEP(k, 0x142, 0xa, false)  // row_bcast:15 -> rows 1,3
  DPP_MAX_STEP(k, 0x143, 0xc, false)  // row_bcast:31 -> rows 2,3
  return k;
}

// ================= FPS =========================================================
// Bit-exact vs numpy: no FMA contraction (contract off), (dx^2+dy^2)+dz^2 order,
// argmax ties -> lowest index (u64 key = bits(d)<<32 | ~i). One barrier/iter;
// phase1 = wave64 DPP reduce -> 4 slots; phase2 = 4-slot read + quad butterfly.
__global__ __launch_bounds__(256) void fps_kernel(const float* __restrict__ xyz,
                                                  int* __restrict__ fps_i,
                                                  float* __restrict__ nxyz_ws,
                                                  float* __restrict__ out)
{
  #pragma clang fp contract(off)
  __shared__ __align__(16) float4 lc[NN];
  __shared__ int lfps[SS];
  __shared__ u64 slotk[2][4];
  int b = blockIdx.x, t = threadIdx.x;
  const float* xb = xyz + (size_t)b*NN*3;
  for (int p = t; p < NN; p += 256){
    lc[p] = make_float4(xb[p*3], xb[p*3+1], xb[p*3+2], 0.f);
  }
  __syncthreads();
  f2 px2[8], py2[8], pz2[8], pd2[8];
  int p0 = t*16;
  #pragma unroll
  for (int j=0;j<8;++j){
    float4 a = lc[p0+2*j], c = lc[p0+2*j+1];
    px2[j] = (f2){a.x, c.x}; py2[j] = (f2){a.y, c.y}; pz2[j] = (f2){a.z, c.z};
    pd2[j] = (f2){F_INF, F_INF};
  }
  float cx = lc[NN/2].x, cy = lc[NN/2].y, cz = lc[NN/2].z;
  if (t==0) lfps[0]=NN/2;
  int wv = t >> 6, lane = t & 63;
  for (int it=1; it<SS; ++it){
    f2 c2x = (f2){cx,cx}, c2y = (f2){cy,cy}, c2z = (f2){cz,cz};
    float bv=-1.f; int bi=p0;
    #pragma unroll
    for (int j=0;j<8;++j){
      f2 dx = px2[j]-c2x, dy = py2[j]-c2y, dz = pz2[j]-c2z;
      f2 d = (dx*dx + dy*dy) + dz*dz;
      f2 nd = (f2){fminf(pd2[j].x, d.x), fminf(pd2[j].y, d.y)};
      pd2[j]=nd;
      if (nd.x > bv){ bv=nd.x; bi=p0+2*j; }
      if (nd.y > bv){ bv=nd.y; bi=p0+2*j+1; }
    }
    u64 key = ((u64)__float_as_uint(bv) << 32) | (unsigned)(~bi);
    key = dpp_wavemax64(key);
    key = __shfl(key, 63);          // readlane broadcast (uniform lane)
    int p = it & 1;
    if (lane == 0) slotk[p][wv] = key;
    __syncthreads();
    u64 k = slotk[p][t & 3];        // 4 addrs, 64-way broadcast each
    DPP_MAX_STEP(k, 0xB1, 0xf, true)   // quad_perm xor1
    DPP_MAX_STEP(k, 0x4E, 0xf, true)   // quad_perm xor2
    int i = ~(unsigned)k;
    float4 cc = lc[i];
    cx = cc.x; cy = cc.y; cz = cc.z;
    if (t==0) lfps[it]=i;
  }
  __syncthreads();
  for (int s=t; s<SS; s+=256){
    int i = lfps[s];
    fps_i[b*SS+s]=i;
    out[OUT_FPS + b*SS + s] = (float)i;
    float4 cc = lc[i];
    int o3 = (b*SS+s)*3;
    out[OUT_NXYZ+o3]=cc.x; out[OUT_NXYZ+o3+1]=cc.y; out[OUT_NXYZ+o3+2]=cc.z;
    nxyz_ws[o3]=cc.x; nxyz_ws[o3+1]=cc.y; nxyz_ws[o3+2]=cc.z;
  }
}

// ================= kNN: 32 smallest dists per (b,s), ties -> lowest index ======
// key = bits(d)<<32 | i  (min, tie -> lowest i); reduce via wave64 DPP max on ~key.
__global__ __launch_bounds__(64) void knn_kernel(const float* __restrict__ xyz,
                                                 const float* __restrict__ nxyz,
                                                 int* __restrict__ knn)
{
  __shared__ float ld[NN];
  int lane = threadIdx.x;
  int bs = blockIdx.x;
  int b = bs >> 10;
  const float* xb = xyz + (size_t)b*NN*3;
  float sx=nxyz[bs*3], sy=nxyz[bs*3+1], sz=nxyz[bs*3+2];
  float gv[8]; int gi[8];
  float lv = F_INF; int li = 0;
  #pragma unroll
  for (int g=0; g<8; ++g){
    float bgv = F_INF; int bgi = 0;
    #pragma unroll
    for (int jj=0; jj<8; ++jj){
      int p = (g*8+jj)*64 + lane;
      float dx=xb[p*3]-sx, dy=xb[p*3+1]-sy, dz=xb[p*3+2]-sz;
      float d = dx*dx+dy*dy+dz*dz;
      ld[p] = d;
      if (d < bgv){ bgv=d; bgi=p; }
    }
    gv[g]=bgv; gi[g]=bgi;
    if (bgv < lv){ lv=bgv; li=bgi; }
  }
  int kept = 0;
  for (int it=0; it<KS; ++it){
    u64 mk = ~(((u64)__float_as_uint(lv) << 32) | (unsigned)li);
    mk = dpp_wavemax64(mk);
    mk = __shfl(mk, 63);
    int i = (int)(unsigned)(~mk);     // low 32 bits of key = index
    if (lane==it) kept = i;
    if ((i & 63) == lane){
      int j = i >> 6;
      ld[i] = F_INF;
      int g = j >> 3;
      float bgv=F_INF; int bgi=0;
      for (int jj=0;jj<8;++jj){
        int p = (g*8+jj)*64 + lane;
        float d = ld[p];
        if (d<bgv){bgv=d;bgi=p;}
      }
      #pragma unroll
      for (int q=0;q<8;++q){ if (q==g){ gv[q]=bgv; gi[q]=bgi; } }
      lv=F_INF; li=0;
      #pragma unroll
      for (int q=0;q<8;++q){ if (gv[q]<lv){ lv=gv[q]; li=gi[q]; } }
    }
  }
  if (lane < KS) knn[bs*KS + lane] = kept;
}

// ================= conv1: gather + MFMA (K=67 padded 96) -> h1 + stats =========
__global__ __launch_bounds__(256) void conv1_kernel(const float* __restrict__ xyz,
                                                    const float* __restrict__ points,
                                                    const float* __restrict__ W0,
                                                    const float* __restrict__ b0,
                                                    const float* __restrict__ nxyz,
                                                    const int* __restrict__ knn,
                                                    bf16* __restrict__ h1,
                                                    float* __restrict__ stats)
{
  __shared__ __align__(16) bf16 As[64][104];
  __shared__ __align__(16) bf16 Bs[64][104];
  __shared__ float s1[C1], s2[C1];
  int t = threadIdx.x;
  int Rbase = blockIdx.x * 64;
  if (t < C1){ s1[t]=0.f; s2[t]=0.f; }
  { // stage B (weights, channel-reordered: feat first, rel at 64..66, zeros to 95)
    int o = t >> 2, q = t & 3;
    const float* wr = W0 + o*INC;
    for (int cc = q*24; cc < q*24+24; ++cc){
      float w;
      if (cc < 64) w = wr[3+cc];
      else if (cc < 67) w = wr[cc-64];
      else w = 0.f;
      Bs[o][cc] = (bf16)w;
    }
  }
  { // stage A (gathered activations)
    int r = t >> 2, q = t & 3;
    int R = Rbase + r;
    int bs = R >> 5;
    int bIdx = bs >> 10;
    int nI = knn[R];
    const float* pr = points + ((size_t)(bIdx*NN + nI))*DF + q*16;
    float4 f0 = *(const float4*)(pr);
    float4 f1 = *(const float4*)(pr+4);
    float4 f2v = *(const float4*)(pr+8);
    float4 f3 = *(const float4*)(pr+12);
    bf16* ap = &As[r][q*16];
    ap[0]=(bf16)f0.x; ap[1]=(bf16)f0.y; ap[2]=(bf16)f0.z; ap[3]=(bf16)f0.w;
    ap[4]=(bf16)f1.x; ap[5]=(bf16)f1.y; ap[6]=(bf16)f1.z; ap[7]=(bf16)f1.w;
    ap[8]=(bf16)f2v.x; ap[9]=(bf16)f2v.y; ap[10]=(bf16)f2v.z; ap[11]=(bf16)f2v.w;
    ap[12]=(bf16)f3.x; ap[13]=(bf16)f3.y; ap[14]=(bf16)f3.z; ap[15]=(bf16)f3.w;
    if (q==0){
      const float* xr = xyz + ((size_t)(bIdx*NN + nI))*3;
      const float* nr = nxyz + bs*3;
      As[r][64]=(bf16)(xr[0]-nr[0]);
      As[r][65]=(bf16)(xr[1]-nr[1]);
      As[r][66]=(bf16)(xr[2]-nr[2]);
      for (int cc=67; cc<96; ++cc) As[r][cc]=(bf16)0.f;
    }
  }
  __syncthreads();
  int wv = t >> 6, lane = t & 63;
  int row16 = wv * 16;
  int arow = lane & 15, kgrp = lane >> 4;
  ffrag acc[4] = {};
  #pragma unroll
  for (int kc = 0; kc < 3; ++kc){
    bfrag af = *(const bfrag*)&As[row16 + arow][kc*32 + kgrp*8];
    #pragma unroll
    for (int nt = 0; nt < 4; ++nt){
      bfrag bfv = *(const bfrag*)&Bs[nt*16 + arow][kc*32 + kgrp*8];
      acc[nt] = __builtin_amdgcn_mfma_f32_16x16x32_bf16(af, bfv, acc[nt], 0,0,0);
    }
  }
  #pragma unroll
  for (int nt=0; nt<4; ++nt){
    int c = nt*16 + arow;
    float bias = b0[c];
    float ls1=0.f, ls2=0.f;
    #pragma unroll
    for (int r=0;r<4;++r){
      float y = acc[nt][r] + bias;
      int grow = Rbase + row16 + kgrp*4 + r;
      h1[(size_t)grow*C1 + c] = (bf16)y;
      ls1 += y; ls2 += y*y;
    }
    ls1 += __shfl_xor(ls1, 16); ls1 += __shfl_xor(ls1, 32);
    ls2 += __shfl_xor(ls2, 16); ls2 += __shfl_xor(ls2, 32);
    if (kgrp==0){ atomicAdd(&s1[c], ls1); atomicAdd(&s2[c], ls2); }
  }
  __syncthreads();
  if (t < C1){
    float* gp = stats + (blockIdx.x & 63)*256;
    atomicAdd(&gp[t], s1[t]);
    atomicAdd(&gp[128 + t], s2[t]);
  }
}

// ================= BN finalize -> affine coeffs ================================
__global__ void bnfin_kernel(const float* __restrict__ stats, const float* __restrict__ g,
                             const float* __restrict__ be, float* __restrict__ bnc, int C)
{
  int c = threadIdx.x; if (c >= C) return;
  float a1=0.f, a2=0.f;
  for (int q=0;q<64;++q){ a1 += stats[q*256+c]; a2 += stats[q*256+128+c]; }
  float inv = 1.f/(float)ROWS;
  float mu = a1*inv; float var = a2*inv - mu*mu;
  float a = g[c]*rsqrtf(var + EPSBN);
  bnc[c] = a; bnc[128+c] = be[c] - mu*a;
}

// ================= conv2: bn1+relu on the fly, MFMA -> h2 + stats ==============
__global__ __launch_bounds__(256) void conv2_kernel(const bf16* __restrict__ h1,
                                                    const float* __restrict__ W1,
                                                    const float* __restrict__ b1,
                                                    const float* __restrict__ bnc,
                                                    bf16* __restrict__ h2,
                                                    float* __restrict__ stats)
{
  __shared__ __align__(16) bf16 As[64][72];
  __shared__ __align__(16) bf16 Bs[64][72];
  __shared__ float s1[C2], s2[C2];
  int t = threadIdx.x;
  int Rbase = blockIdx.x * 64;
  if (t < C2){ s1[t]=0.f; s2[t]=0.f; }
  {
    int o = t >> 2, q = t & 3;
    const float* wr = W1 + o*64 + q*16;
    bf16* bp = &Bs[o][q*16];
    #pragma unroll
    for (int v=0; v<4; ++v){
      float4 f = *(const float4*)(wr + v*4);
      bp[v*4+0]=(bf16)f.x; bp[v*4+1]=(bf16)f.y; bp[v*4+2]=(bf16)f.z; bp[v*4+3]=(bf16)f.w;
    }
  }
  {
    int r = t >> 2, q = t & 3;
    int R = Rbase + r;
    const bf16* hr = h1 + (size_t)R*64 + q*16;
    bfrag h0 = *(const bfrag*)hr;
    bfrag h1v = *(const bfrag*)(hr+8);
    #pragma unroll
    for (int j=0;j<8;++j){
      int c=q*16+j;
      As[r][c] = (bf16)fmaxf(fmaf(bnc[c], (float)h0[j], bnc[128+c]), 0.f);
    }
    #pragma unroll
    for (int j=0;j<8;++j){
      int c=q*16+8+j;
      As[r][c] = (bf16)fmaxf(fmaf(bnc[c], (float)h1v[j], bnc[128+c]), 0.f);
    }
  }
  __syncthreads();
  int wv = t >> 6, lane = t & 63;
  int row16 = wv * 16;
  int arow = lane & 15, kgrp = lane >> 4;
  ffrag acc[4] = {};
  #pragma unroll
  for (int kc = 0; kc < 2; ++kc){
    bfrag af = *(const bfrag*)&As[row16 + arow][kc*32 + kgrp*8];
    #pragma unroll
    for (int nt = 0; nt < 4; ++nt){
      bfrag bfv = *(const bfrag*)&Bs[nt*16 + arow][kc*32 + kgrp*8];
      acc[nt] = __builtin_amdgcn_mfma_f32_16x16x32_bf16(af, bfv, acc[nt], 0,0,0);
    }
  }
  #pragma unroll
  for (int nt=0; nt<4; ++nt){
    int c = nt*16 + arow;
    float bias = b1[c];
    float ls1=0.f, ls2=0.f;
    #pragma unroll
    for (int r=0;r<4;++r){
      float y = acc[nt][r] + bias;
      int grow = Rbase + row16 + kgrp*4 + r;
      h2[(size_t)grow*C2 + c] = (bf16)y;
      ls1 += y; ls2 += y*y;
    }
    ls1 += __shfl_xor(ls1, 16); ls1 += __shfl_xor(ls1, 32);
    ls2 += __shfl_xor(ls2, 16); ls2 += __shfl_xor(ls2, 32);
    if (kgrp==0){ atomicAdd(&s1[c], ls1); atomicAdd(&s2[c], ls2); }
  }
  __syncthreads();
  if (t < C2){
    float* gp = stats + (blockIdx.x & 63)*256;
    atomicAdd(&gp[t], s1[t]);
    atomicAdd(&gp[128 + t], s2[t]);
  }
}

// ========= conv3: bn2+relu, MFMA (N=128), in-block maxpool over k -> ymax ======
__global__ __launch_bounds__(256) void conv3_kernel(const bf16* __restrict__ h2,
                                                    const float* __restrict__ W2,
                                                    const float* __restrict__ b2,
                                                    const float* __restrict__ bnc,
                                                    float* __restrict__ ymax,
                                                    float* __restrict__ stats)
{
  __shared__ __align__(16) bf16 As[64][72];
  __shared__ __align__(16) bf16 Bs[128][72];
  __shared__ float s1[C3], s2[C3];
  __shared__ float wmax[4][C3];
  int t = threadIdx.x;
  int Rbase = blockIdx.x * 64;
  if (t < C3){ s1[t]=0.f; s2[t]=0.f; }
  {
    int o = t >> 1, q = t & 1;
    const float* wr = W2 + o*64 + q*32;
    bf16* bp = &Bs[o][q*32];
    #pragma unroll
    for (int v=0; v<8; ++v){
      float4 f = *(const float4*)(wr + v*4);
      bp[v*4+0]=(bf16)f.x; bp[v*4+1]=(bf16)f.y; bp[v*4+2]=(bf16)f.z; bp[v*4+3]=(bf16)f.w;
    }
  }
  {
    int r = t >> 2, q = t & 3;
    int R = Rbase + r;
    const bf16* hr = h2 + (size_t)R*64 + q*16;
    bfrag h0 = *(const bfrag*)hr;
    bfrag h1v = *(const bfrag*)(hr+8);
    #pragma unroll
    for (int j=0;j<8;++j){
      int c=q*16+j;
      As[r][c] = (bf16)fmaxf(fmaf(bnc[c], (float)h0[j], bnc[128+c]), 0.f);
    }
    #pragma unroll
    for (int j=0;j<8;++j){
      int c=q*16+8+j;
      As[r][c] = (bf16)fmaxf(fmaf(bnc[c], (float)h1v[j], bnc[128+c]), 0.f);
    }
  }
  __syncthreads();
  int wv = t >> 6, lane = t & 63;
  int row16 = wv * 16;
  int arow = lane & 15, kgrp = lane >> 4;
  ffrag acc[8] = {};
  #pragma unroll
  for (int kc = 0; kc < 2; ++kc){
    bfrag af = *(const bfrag*)&As[row16 + arow][kc*32 + kgrp*8];
    #pragma unroll
    for (int nt = 0; nt < 8; ++nt){
      bfrag bfv = *(const bfrag*)&Bs[nt*16 + arow][kc*32 + kgrp*8];
      acc[nt] = __builtin_amdgcn_mfma_f32_16x16x32_bf16(af, bfv, acc[nt], 0,0,0);
    }
  }
  #pragma unroll
  for (int nt=0; nt<8; ++nt){
    int c = nt*16 + arow;
    float bias = b2[c];
    float ls1=0.f, ls2=0.f, mm=-F_INF;
    #pragma unroll
    for (int r=0;r<4;++r){
      float y = acc[nt][r] + bias;
      ls1 += y; ls2 += y*y; mm = fmaxf(mm, y);
    }
    ls1 += __shfl_xor(ls1, 16); ls1 += __shfl_xor(ls1, 32);
    ls2 += __shfl_xor(ls2, 16); ls2 += __shfl_xor(ls2, 32);
    mm = fmaxf(mm, __shfl_xor(mm, 16)); mm = fmaxf(mm, __shfl_xor(mm, 32));
    if (kgrp==0){ atomicAdd(&s1[c], ls1); atomicAdd(&s2[c], ls2); wmax[wv][c]=mm; }
  }
  __syncthreads();
  {
    int half = t >> 7;
    int c = t & 127;
    float m = fmaxf(wmax[half*2][c], wmax[half*2+1][c]);
    ymax[(size_t)(blockIdx.x*2 + half)*C3 + c] = m;
  }
  if (t < C3){
    float* gp = stats + (blockIdx.x & 63)*256;
    atomicAdd(&gp[t], s1[t]);
    atomicAdd(&gp[128 + t], s2[t]);
  }
}

// === bn3+relu (valid: a3>0) + np0 write + avg/max reduction, fused =============
__global__ __launch_bounds__(256) void attreduce_kernel(const float* __restrict__ ymax,
                                                        const float* __restrict__ bnc,
                                                        float* __restrict__ np0,
                                                        float* __restrict__ asum,
                                                        unsigned* __restrict__ amax)
{
  __shared__ float rs[256], rm[256];
  int t = threadIdx.x;
  int b = blockIdx.x >> 3, sg = blockIdx.x & 7;
  int c = t & 127, h = t >> 7;
  float a = bnc[c], bb = bnc[128+c];
  size_t base = ((size_t)(b*1024 + sg*128 + h*64))*128 + c;
  float s = 0.f, m = 0.f;
  #pragma unroll 4
  for (int j=0;j<64;++j){
    float v = fmaxf(fmaf(a, ymax[base + (size_t)j*128], bb), 0.f);
    np0[base + (size_t)j*128] = v;
    s += v; m = fmaxf(m, v);
  }
  rs[t]=s; rm[t]=m;
  __syncthreads();
  if (t < 128){
    float s2 = rs[t] + rs[t+128];
    float m2 = fmaxf(rm[t], rm[t+128]);
    atomicAdd(&asum[b*128+t], s2);
    atomicMax(&amax[b*128+t], __float_as_uint(m2));
  }
}

// ================= channel attention (tiny) ====================================
__global__ __launch_bounds__(256) void attn_kernel(const float* __restrict__ asum,
                                                   const unsigned* __restrict__ amax,
                                                   const float* __restrict__ aW1,
                                                   const float* __restrict__ aW2,
                                                   float* __restrict__ scale)
{
  __shared__ float avg[16][128], mx[16][128], hA[16][16], hM[16][16];
  int t = threadIdx.x;
  for (int i=t; i<2048; i+=256){
    int b=i>>7, c=i&127;
    avg[b][c]=asum[i]*(1.f/1024.f); mx[b][c]=__uint_as_float(amax[i]);
  }
  __syncthreads();
  {
    int b=t>>4, r=t&15;
    float sa=0.f, sm=0.f;
    for (int c=0;c<128;++c){ float w=aW1[r*128+c]; sa+=w*avg[b][c]; sm+=w*mx[b][c]; }
    hA[b][r]=fmaxf(sa,0.f); hM[b][r]=fmaxf(sm,0.f);
  }
  __syncthreads();
  for (int i=t;i<2048;i+=256){
    int b=i>>7,c=i&127;
    float o=0.f;
    for (int r=0;r<16;++r){ o += aW2[c*16+r]*(hA[b][r]+hM[b][r]); }
    scale[i] = 1.f/(1.f+expf(-o));
  }
}

// ================= final scale + write =========================================
__global__ __launch_bounds__(256) void finout_kernel(const float* __restrict__ np0,
                                                     const float* __restrict__ scale,
                                                     float* __restrict__ out)
{
  int i = blockIdx.x*256 + threadIdx.x;
  int c = i & 127; int b = i >> 17;
  out[OUT_NP + i] = np0[i] * scale[b*128+c];
}

extern "C" void kernel_launch(void* const* d_in, const int* in_sizes, int n_in,
                              void* d_out, int out_size, void* d_ws, size_t ws_size,
                              hipStream_t stream)
{
  const float* xyz    = (const float*)d_in[0];
  const float* points = (const float*)d_in[1];
  const float* W0 = (const float*)d_in[2];
  const float* b0 = (const float*)d_in[3];
  const float* g0 = (const float*)d_in[4];
  const float* be0= (const float*)d_in[5];
  const float* W1 = (const float*)d_in[6];
  const float* b1 = (const float*)d_in[7];
  const float* g1 = (const float*)d_in[8];
  const float* be1= (const float*)d_in[9];
  const float* W2 = (const float*)d_in[10];
  const float* b2 = (const float*)d_in[11];
  const float* g2 = (const float*)d_in[12];
  const float* be2= (const float*)d_in[13];
  const float* aW1= (const float*)d_in[14];
  const float* aW2= (const float*)d_in[15];
  float* out = (float*)d_out;
  char* ws = (char*)d_ws;

  int*      fpsI  = (int*)(ws + OFF_FPS);
  float*    nxyz  = (float*)(ws + OFF_NXYZ);
  int*      knnI  = (int*)(ws + OFF_IDX);
  float*    stats = (float*)(ws + OFF_STATS);
  float*    asum  = (float*)(ws + OFF_ASUM);
  unsigned* amax  = (unsigned*)(ws + OFF_AMAX);
  float*    bnc   = (float*)(ws + OFF_BNC);
  float*    scl   = (float*)(ws + OFF_SCALE);
  float*    np0   = (float*)(ws + OFF_NP0);
  float*    ymax  = (float*)(ws + OFF_YMAX);
  bf16*     h1    = (bf16*)(ws + OFF_H1);
  bf16*     h2    = (bf16*)(ws + OFF_H2);

  hipMemsetAsync(ws + OFF_STATS, 0, ZERO_BYTES, stream);
  fps_kernel<<<BB, 256, 0, stream>>>(xyz, fpsI, nxyz, out);
  knn_kernel<<<BB*SS, 64, 0, stream>>>(xyz, nxyz, knnI);
  conv1_kernel<<<ROWS/64, 256, 0, stream>>>(xyz, points, W0, b0, nxyz, knnI, h1, stats);
  bnfin_kernel<<<1, 128, 0, stream>>>(stats, g0, be0, bnc, C1);
  conv2_kernel<<<ROWS/64, 256, 0, stream>>>(h1, W1, b1, bnc, h2, stats + 64*256);
  bnfin_kernel<<<1, 128, 0, stream>>>(stats + 64*256, g1, be1, bnc + 256, C2);
  conv3_kernel<<<ROWS/64, 256, 0, stream>>>(h2, W2, b2, bnc + 256, ymax, stats + 2*64*256);
  bnfin_kernel<<<1, 128, 0, stream>>>(stats + 2*64*256, g2, be2, bnc + 512, C3);
  attreduce_kernel<<<BB*8, 256, 0, stream>>>(ymax, bnc + 512, np0, asum, amax);
  attn_kernel<<<1, 256, 0, stream>>>(asum, amax, aW1, aW2, scl);
  finout_kernel<<<(BB*SS*C3)/256, 256, 0, stream>>>(np0, scl, out);
}